// Round 1
// baseline (9545.319 us; speedup 1.0000x reference)
//
#include <hip/hip_runtime.h>
#include <math.h>

#define N_NODES 50000
#define E_EDGES 320000
#define DIN_    768
#define D_      256
#define R_TYPES 4
#define L_LAYERS 3
#define BATCH_  64
#define T_STEPS 6
#define SD_     128
#define SH_     256
#define NC_     14
#define ALPHA_  0.15f

// ---------------- generic fp32 linear: out[m,n] = sum_k A[m,k]*W[n,k] + bias[n]
// 64x64 tile, BK=16, 256 threads, 4x4 per thread. Optionally dual-store (h0 and h).
__global__ __launch_bounds__(256) void linear_kernel(
    const float* __restrict__ A, const float* __restrict__ W,
    const float* __restrict__ bias, float* __restrict__ out,
    float* __restrict__ out2, int M, int K, int N)
{
    __shared__ float As[16][68];
    __shared__ float Bs[16][68];
    const int m0 = blockIdx.x * 64;
    const int n0 = blockIdx.y * 64;
    const int tid = threadIdx.x;
    const int kk = tid & 15;   // k within tile
    const int rr = tid >> 4;   // row group
    const int tx = tid & 15, ty = tid >> 4;
    float acc[4][4] = {};
    for (int k0 = 0; k0 < K; k0 += 16) {
        #pragma unroll
        for (int i = 0; i < 4; i++) {
            int m = m0 + rr + 16 * i;
            As[kk][rr + 16 * i] = (m < M) ? A[(size_t)m * K + k0 + kk] : 0.0f;
            int n = n0 + rr + 16 * i;
            Bs[kk][rr + 16 * i] = W[(size_t)n * K + k0 + kk];
        }
        __syncthreads();
        #pragma unroll
        for (int k = 0; k < 16; k++) {
            float4 a4 = *(const float4*)&As[k][ty * 4];
            float4 b4 = *(const float4*)&Bs[k][tx * 4];
            float av[4] = {a4.x, a4.y, a4.z, a4.w};
            float bv[4] = {b4.x, b4.y, b4.z, b4.w};
            #pragma unroll
            for (int i = 0; i < 4; i++)
                #pragma unroll
                for (int j = 0; j < 4; j++)
                    acc[i][j] += av[i] * bv[j];
        }
        __syncthreads();
    }
    #pragma unroll
    for (int i = 0; i < 4; i++) {
        int m = m0 + ty * 4 + i;
        if (m >= M) continue;
        #pragma unroll
        for (int j = 0; j < 4; j++) {
            int n = n0 + tx * 4 + j;
            float v = acc[i][j] + (bias ? bias[n] : 0.0f);
            out[(size_t)m * N + n] = v;
            if (out2) out2[(size_t)m * N + n] = v;
        }
    }
}

// ---------------- edge bucketing by type (counting sort)
__global__ void bucket_count_kernel(const int* __restrict__ et, int* __restrict__ cnt)
{
    for (int e = blockIdx.x * blockDim.x + threadIdx.x; e < E_EDGES; e += gridDim.x * blockDim.x)
        atomicAdd(&cnt[et[e]], 1);
}
__global__ void bucket_offsets_kernel(const int* __restrict__ cnt, int* __restrict__ boff, int* __restrict__ cursor)
{
    if (threadIdx.x == 0) {
        int o = 0;
        for (int r = 0; r < R_TYPES; r++) { boff[r] = o; cursor[r] = o; o += cnt[r]; }
        boff[R_TYPES] = o;
    }
}
__global__ void bucket_scatter_kernel(const int* __restrict__ ei, const int* __restrict__ et,
                                      int* __restrict__ cursor, int* __restrict__ bsrc, int* __restrict__ bdst)
{
    for (int e = blockIdx.x * blockDim.x + threadIdx.x; e < E_EDGES; e += gridDim.x * blockDim.x) {
        int r = et[e];
        int pos = atomicAdd(&cursor[r], 1);
        bsrc[pos] = ei[e];             // src = edge_index[0]
        bdst[pos] = ei[E_EDGES + e];   // dst = edge_index[1]
    }
}

__global__ void embmean_kernel(const float* __restrict__ emb, float* __restrict__ em)
{
    int lr = threadIdx.x;
    if (lr < L_LAYERS * R_TYPES) {
        float s = 0.0f;
        for (int k = 0; k < 64; k++) s += emb[lr * 64 + k];
        em[lr] = s / 64.0f;
    }
}

// ---------------- fused attention score: s[p] = lrelu(relu(cat@W1.T + b1)@W2 + b2) + embmean
// cat[e] = [h[dst], h[src]] (512). tile: 64 edges x 128 hidden, BK=16.
__global__ __launch_bounds__(256) void attn_score_kernel(
    const float* __restrict__ h, const int* __restrict__ bsrc, const int* __restrict__ bdst,
    const int* __restrict__ boff, int r,
    const float* __restrict__ W1, const float* __restrict__ b1,
    const float* __restrict__ W2, const float* __restrict__ b2s,
    const float* __restrict__ em, int lr, float* __restrict__ sbuf)
{
    const int off = boff[r];
    const int n_r = boff[r + 1] - off;
    const int p0 = blockIdx.x * 64;
    if (p0 >= n_r) return;
    __shared__ int nd_d[64], nd_s[64];
    __shared__ float Cs[16][68];
    __shared__ float W1s[16][132];
    __shared__ float red[64][17];
    const int tid = threadIdx.x;
    if (tid < 64) nd_d[tid] = (p0 + tid < n_r) ? bdst[off + p0 + tid] : 0;
    else if (tid < 128) { int t = tid - 64; nd_s[t] = (p0 + t < n_r) ? bsrc[off + p0 + t] : 0; }
    __syncthreads();
    const int kk = tid & 15, rr = tid >> 4;
    const int tx = tid & 15, ty = tid >> 4;
    float acc[4][8] = {};
    for (int k0 = 0; k0 < 512; k0 += 16) {
        const bool useDst = (k0 < 256);
        const int koff = useDst ? k0 : (k0 - 256);
        #pragma unroll
        for (int i = 0; i < 4; i++) {
            int le = rr + 16 * i;
            int node = useDst ? nd_d[le] : nd_s[le];
            Cs[kk][le] = h[(size_t)node * D_ + koff + kk];
        }
        #pragma unroll
        for (int i = 0; i < 8; i++) {
            int n = rr + 16 * i;
            W1s[kk][n] = W1[(size_t)n * 512 + k0 + kk];
        }
        __syncthreads();
        #pragma unroll
        for (int k = 0; k < 16; k++) {
            float4 c4 = *(const float4*)&Cs[k][ty * 4];
            float4 wa = *(const float4*)&W1s[k][tx * 8];
            float4 wb = *(const float4*)&W1s[k][tx * 8 + 4];
            float cv[4] = {c4.x, c4.y, c4.z, c4.w};
            float wv[8] = {wa.x, wa.y, wa.z, wa.w, wb.x, wb.y, wb.z, wb.w};
            #pragma unroll
            for (int i = 0; i < 4; i++)
                #pragma unroll
                for (int j = 0; j < 8; j++)
                    acc[i][j] += cv[i] * wv[j];
        }
        __syncthreads();
    }
    float part[4] = {0, 0, 0, 0};
    #pragma unroll
    for (int j = 0; j < 8; j++) {
        int n = tx * 8 + j;
        float b1v = b1[n], w2v = W2[n];
        #pragma unroll
        for (int i = 0; i < 4; i++) {
            float v = acc[i][j] + b1v;
            v = v > 0.0f ? v : 0.0f;
            part[i] += v * w2v;
        }
    }
    #pragma unroll
    for (int i = 0; i < 4; i++) red[ty * 4 + i][tx] = part[i];
    __syncthreads();
    if (tid < 64) {
        float s = 0.0f;
        #pragma unroll
        for (int x = 0; x < 16; x++) s += red[tid][x];
        int p = p0 + tid;
        if (p < n_r) {
            float sv = s + b2s[0];
            sv = sv > 0.0f ? sv : 0.2f * sv;   // leaky_relu(0.2)
            sv += em[lr];
            sbuf[p] = sv;
        }
    }
}

// ---------------- masked-softmax helpers (monotonic uint key for float atomicMax)
__device__ __forceinline__ unsigned fkey(float f) {
    unsigned u = __float_as_uint(f);
    return (u & 0x80000000u) ? ~u : (u | 0x80000000u);
}
__device__ __forceinline__ float fkey_inv(unsigned k) {
    unsigned u = (k & 0x80000000u) ? (k ^ 0x80000000u) : ~k;
    return __uint_as_float(u);
}

__global__ void bucket_max_kernel(const float* __restrict__ sbuf, const int* __restrict__ boff,
                                  int r, unsigned* __restrict__ mx)
{
    int n_r = boff[r + 1] - boff[r];
    float m = -1e30f;
    for (int i = blockIdx.x * blockDim.x + threadIdx.x; i < n_r; i += gridDim.x * blockDim.x)
        m = fmaxf(m, sbuf[i]);
    for (int o = 32; o; o >>= 1) m = fmaxf(m, __shfl_down(m, o));
    __shared__ float wm[4];
    int lane = threadIdx.x & 63, wv = threadIdx.x >> 6;
    if (lane == 0) wm[wv] = m;
    __syncthreads();
    if (threadIdx.x == 0) {
        float b = fmaxf(fmaxf(wm[0], wm[1]), fmaxf(wm[2], wm[3]));
        atomicMax(mx, fkey(b));
    }
}

__global__ void bucket_sum_kernel(const float* __restrict__ sbuf, const int* __restrict__ boff,
                                  int r, const unsigned* __restrict__ mx, float* __restrict__ sum)
{
    int n_r = boff[r + 1] - boff[r];
    float mxf = fkey_inv(*mx);
    float s = 0.0f;
    for (int i = blockIdx.x * blockDim.x + threadIdx.x; i < n_r; i += gridDim.x * blockDim.x)
        s += expf(sbuf[i] - mxf);
    for (int o = 32; o; o >>= 1) s += __shfl_down(s, o);
    __shared__ float wm[4];
    int lane = threadIdx.x & 63, wv = threadIdx.x >> 6;
    if (lane == 0) wm[wv] = s;
    __syncthreads();
    if (threadIdx.x == 0) atomicAdd(sum, wm[0] + wm[1] + wm[2] + wm[3]);
}

// ---------------- message passing: acc[dst] += (1-a)*ew[r] * softmax(s) * tx[src]
__global__ void message_kernel(const float* __restrict__ sbuf, const float* __restrict__ txb,
                               const int* __restrict__ bsrc, const int* __restrict__ bdst,
                               const int* __restrict__ boff, int r,
                               const unsigned* __restrict__ mx, const float* __restrict__ sumv,
                               const float* __restrict__ imp, int l, float* __restrict__ acc)
{
    const int off = boff[r];
    const int n_r = boff[r + 1] - off;
    const float mxf = fkey_inv(*mx);
    const float inv = 1.0f / sumv[0];
    float e0 = expf(imp[l * 4 + 0]), e1 = expf(imp[l * 4 + 1]);
    float e2 = expf(imp[l * 4 + 2]), e3 = expf(imp[l * 4 + 3]);
    float ew = ((r == 0) ? e0 : (r == 1) ? e1 : (r == 2) ? e2 : e3) / (e0 + e1 + e2 + e3);
    const float coef = (1.0f - ALPHA_) * ew;
    const int lane = threadIdx.x & 63;
    const int eslot = threadIdx.x >> 6;
    for (int base = blockIdx.x * 4; base < n_r; base += gridDim.x * 4) {
        int p = base + eslot;
        if (p >= n_r) continue;
        float a = expf(sbuf[p] - mxf) * inv * coef;
        int s = bsrc[off + p], d = bdst[off + p];
        const float* txp = txb + (size_t)s * D_;
        float* ap = acc + (size_t)d * D_;
        #pragma unroll
        for (int j = 0; j < 4; j++) {
            int c = lane + 64 * j;
            atomicAdd(&ap[c], a * txp[c]);
        }
    }
}

// ---------------- out = LN(acc + alpha*h0) -> exact GELU ; one wave per node
__global__ __launch_bounds__(256) void finalize_kernel(
    const float* __restrict__ acc, const float* __restrict__ h0,
    const float* __restrict__ g, const float* __restrict__ b,
    float* __restrict__ h, int Nn)
{
    int node = blockIdx.x * 4 + (threadIdx.x >> 6);
    if (node >= Nn) return;
    int lane = threadIdx.x & 63;
    float v[4];
    float sum = 0.0f;
    #pragma unroll
    for (int j = 0; j < 4; j++) {
        int c = lane + 64 * j;
        v[j] = acc[(size_t)node * D_ + c] + ALPHA_ * h0[(size_t)node * D_ + c];
        sum += v[j];
    }
    #pragma unroll
    for (int o = 32; o; o >>= 1) sum += __shfl_down(sum, o);
    sum = __shfl(sum, 0);
    float mean = sum * (1.0f / 256.0f);
    float sq = 0.0f;
    #pragma unroll
    for (int j = 0; j < 4; j++) { float d = v[j] - mean; sq += d * d; }
    #pragma unroll
    for (int o = 32; o; o >>= 1) sq += __shfl_down(sq, o);
    sq = __shfl(sq, 0);
    float rstd = rsqrtf(sq * (1.0f / 256.0f) + 1e-5f);
    #pragma unroll
    for (int j = 0; j < 4; j++) {
        int c = lane + 64 * j;
        float x = (v[j] - mean) * rstd * g[c] + b[c];
        float ge = 0.5f * x * (1.0f + erff(x * 0.7071067811865475f));
        h[(size_t)node * D_ + c] = ge;
    }
}

// ---------------- graph mean-pool (atomic) + count
__global__ void pool_kernel(const float* __restrict__ h, const int* __restrict__ batch,
                            float* __restrict__ pooled, float* __restrict__ cntb, int Nn)
{
    int node = blockIdx.x;
    if (node >= Nn) return;
    int b = batch[node];
    int c = threadIdx.x;
    atomicAdd(&pooled[b * D_ + c], h[(size_t)node * D_ + c]);
    if (c == 0) atomicAdd(&cntb[b], 1.0f);
}

// ---------------- graph MLP head (+ add seq logits) -> d_out
__global__ __launch_bounds__(256) void final_mlp_kernel(
    const float* __restrict__ pooled, const float* __restrict__ cntb,
    const float* __restrict__ W1, const float* __restrict__ b1,
    const float* __restrict__ W2, const float* __restrict__ b2,
    const float* __restrict__ W3, const float* __restrict__ b3,
    const float* __restrict__ seqlg, float* __restrict__ out)
{
    int b = blockIdx.x;
    int t = threadIdx.x;
    __shared__ float p[256];
    __shared__ float z1[128];
    __shared__ float z2[64];
    float c = cntb[b]; c = c < 1.0f ? 1.0f : c;
    p[t] = pooled[b * 256 + t] / c;
    __syncthreads();
    if (t < 128) {
        float s = b1[t];
        for (int k = 0; k < 256; k++) s += p[k] * W1[t * 256 + k];
        z1[t] = s > 0.0f ? s : 0.0f;
    }
    __syncthreads();
    if (t < 64) {
        float s = b2[t];
        for (int k = 0; k < 128; k++) s += z1[k] * W2[t * 128 + k];
        z2[t] = s > 0.0f ? s : 0.0f;
    }
    __syncthreads();
    if (t < NC_) {
        float s = b3[t];
        for (int k = 0; k < 64; k++) s += z2[k] * W3[t * 64 + k];
        out[b * NC_ + t] = s + seqlg[b * NC_ + t];
    }
}

// ---------------- GRU: one step for both directions; block = (b, dir)
__global__ __launch_bounds__(256) void gru_step_kernel(
    const float* __restrict__ seq, const float* __restrict__ Wih, const float* __restrict__ Whh,
    const float* __restrict__ bih, const float* __restrict__ bhh,
    float* __restrict__ hstate, float* __restrict__ outs, int t)
{
    int blk = blockIdx.x;      // 0..127
    int dir = blk >> 6;
    int b = blk & 63;
    int tin = dir ? (T_STEPS - 1 - t) : t;   // bwd consumes reversed input; output also lands at tin
    const float* Wih_d = Wih + (size_t)dir * (3 * SH_) * SD_;
    const float* Whh_d = Whh + (size_t)dir * (3 * SH_) * SH_;
    const float* bih_d = bih + dir * (3 * SH_);
    const float* bhh_d = bhh + dir * (3 * SH_);
    __shared__ float xt[SD_];
    __shared__ float hs[SH_];
    int j = threadIdx.x;
    if (j < SD_) xt[j] = seq[((size_t)b * T_STEPS + tin) * SD_ + j];
    hs[j] = hstate[((size_t)dir * 64 + b) * SH_ + j];
    __syncthreads();
    float gi[3], gh[3];
    #pragma unroll
    for (int g = 0; g < 3; g++) {
        const float* wrow = Wih_d + (size_t)(g * SH_ + j) * SD_;
        float s = bih_d[g * SH_ + j];
        for (int k = 0; k < SD_; k++) s += xt[k] * wrow[k];
        gi[g] = s;
        const float* hrow = Whh_d + (size_t)(g * SH_ + j) * SH_;
        float s2 = bhh_d[g * SH_ + j];
        for (int k = 0; k < SH_; k++) s2 += hs[k] * hrow[k];
        gh[g] = s2;
    }
    float r = 1.0f / (1.0f + expf(-(gi[0] + gh[0])));
    float z = 1.0f / (1.0f + expf(-(gi[1] + gh[1])));
    float n = tanhf(gi[2] + r * gh[2]);
    float hn = (1.0f - z) * n + z * hs[j];
    hstate[((size_t)dir * 64 + b) * SH_ + j] = hn;
    outs[(((size_t)dir * 64 + b) * T_STEPS + tin) * SH_ + j] = hn;
}

// ---------------- seq branch: mean+max pool over T, 3-layer MLP -> seq logits
__global__ __launch_bounds__(256) void seq_mlp_kernel(
    const float* __restrict__ outs, const float* __restrict__ W1, const float* __restrict__ b1,
    const float* __restrict__ W2, const float* __restrict__ b2,
    const float* __restrict__ W3, const float* __restrict__ b3,
    float* __restrict__ seqlg)
{
    int b = blockIdx.x;
    int t = threadIdx.x;
    __shared__ float z[512];
    __shared__ float z1[256];
    __shared__ float z2[128];
    for (int c = t; c < 512; c += 256) {
        int dir = c >> 8, cc = c & 255;
        float mean = 0.0f, mx = -1e30f;
        for (int tt = 0; tt < T_STEPS; tt++) {
            float v = outs[(((size_t)dir * 64 + b) * T_STEPS + tt) * SH_ + cc];
            mean += v; mx = fmaxf(mx, v);
        }
        z[c] = mean * (1.0f / T_STEPS) + mx;
    }
    __syncthreads();
    {
        float s = b1[t];
        for (int k = 0; k < 512; k++) s += z[k] * W1[t * 512 + k];
        z1[t] = s > 0.0f ? s : 0.0f;
    }
    __syncthreads();
    if (t < 128) {
        float s = b2[t];
        for (int k = 0; k < 256; k++) s += z1[k] * W2[t * 256 + k];
        z2[t] = s > 0.0f ? s : 0.0f;
    }
    __syncthreads();
    if (t < NC_) {
        float s = b3[t];
        for (int k = 0; k < 128; k++) s += z2[k] * W3[t * 128 + k];
        seqlg[b * NC_ + t] = s;
    }
}

extern "C" void kernel_launch(void* const* d_in, const int* in_sizes, int n_in,
                              void* d_out, int out_size, void* d_ws, size_t ws_size,
                              hipStream_t stream)
{
    const float* x      = (const float*)d_in[0];
    const int*   ei     = (const int*)d_in[1];
    const int*   et     = (const int*)d_in[2];
    const int*   batch  = (const int*)d_in[3];
    const float* seq    = (const float*)d_in[4];
    const float* proj_W = (const float*)d_in[5];
    const float* proj_b = (const float*)d_in[6];
    const float* Wr     = (const float*)d_in[7];
    const float* Ws     = (const float*)d_in[8];
    const float* bs     = (const float*)d_in[9];
    const float* aW1    = (const float*)d_in[10];
    const float* ab1    = (const float*)d_in[11];
    const float* aW2    = (const float*)d_in[12];
    const float* ab2    = (const float*)d_in[13];
    const float* emb    = (const float*)d_in[14];
    const float* imp    = (const float*)d_in[15];
    const float* ln_g   = (const float*)d_in[16];
    const float* ln_b   = (const float*)d_in[17];
    const float* gmW1   = (const float*)d_in[18];
    const float* gmb1   = (const float*)d_in[19];
    const float* gmW2   = (const float*)d_in[20];
    const float* gmb2   = (const float*)d_in[21];
    const float* gmW3   = (const float*)d_in[22];
    const float* gmb3   = (const float*)d_in[23];
    const float* gWih   = (const float*)d_in[24];
    const float* gWhh   = (const float*)d_in[25];
    const float* gbih   = (const float*)d_in[26];
    const float* gbhh   = (const float*)d_in[27];
    const float* smW1   = (const float*)d_in[28];
    const float* smb1   = (const float*)d_in[29];
    const float* smW2   = (const float*)d_in[30];
    const float* smb2   = (const float*)d_in[31];
    const float* smW3   = (const float*)d_in[32];
    const float* smb3   = (const float*)d_in[33];
    float* out = (float*)d_out;

    // ---- workspace layout (~211 MB)
    char* ws = (char*)d_ws;
    size_t o = 0;
    auto alloc = [&](size_t bytes) -> void* {
        void* p = ws + o;
        o += (bytes + 1023) & ~(size_t)1023;
        return p;
    };
    float* h0     = (float*)alloc(sizeof(float) * (size_t)N_NODES * D_);
    float* h      = (float*)alloc(sizeof(float) * (size_t)N_NODES * D_);
    float* accb   = (float*)alloc(sizeof(float) * (size_t)N_NODES * D_);
    float* txb    = (float*)alloc(sizeof(float) * (size_t)N_NODES * D_);
    float* sbuf   = (float*)alloc(sizeof(float) * E_EDGES);
    int*   bsrc   = (int*)alloc(sizeof(int) * E_EDGES);
    int*   bdst   = (int*)alloc(sizeof(int) * E_EDGES);
    int*   ictl   = (int*)alloc(sizeof(int) * 16);      // cnt[4], cursor[4], boff[5]
    int*   cnt4   = ictl;
    int*   cursor = ictl + 4;
    int*   boff   = ictl + 8;
    unsigned* red = (unsigned*)alloc(sizeof(unsigned) * 32); // per (l,r): [2*lr]=max key, [2*lr+1]=sum(float)
    float* em     = (float*)alloc(sizeof(float) * 16);
    float* seqlg  = (float*)alloc(sizeof(float) * BATCH_ * NC_);
    float* gruH   = (float*)alloc(sizeof(float) * 2 * BATCH_ * SH_);
    float* gruO   = (float*)alloc(sizeof(float) * 2 * BATCH_ * T_STEPS * SH_);
    float* pooled = (float*)alloc(sizeof(float) * BATCH_ * D_);
    float* cntb   = (float*)alloc(sizeof(float) * BATCH_);
    (void)ws_size; (void)in_sizes; (void)n_in; (void)out_size;

    // ---- zero-init (ws is poisoned 0xAA before every timed launch)
    hipMemsetAsync(ictl, 0, 16 * sizeof(int), stream);
    hipMemsetAsync(red, 0, 32 * sizeof(unsigned), stream);          // key 0 < any real fkey; sum = 0.0f
    hipMemsetAsync(gruH, 0, 2 * BATCH_ * SH_ * sizeof(float), stream);
    hipMemsetAsync(pooled, 0, BATCH_ * D_ * sizeof(float), stream);
    hipMemsetAsync(cntb, 0, BATCH_ * sizeof(float), stream);

    // ---- edge bucketing by type
    bucket_count_kernel<<<512, 256, 0, stream>>>(et, cnt4);
    bucket_offsets_kernel<<<1, 64, 0, stream>>>(cnt4, boff, cursor);
    bucket_scatter_kernel<<<512, 256, 0, stream>>>(ei, et, cursor, bsrc, bdst);
    embmean_kernel<<<1, 64, 0, stream>>>(emb, em);

    // ---- sequence branch
    for (int t = 0; t < T_STEPS; t++)
        gru_step_kernel<<<128, 256, 0, stream>>>(seq, gWih, gWhh, gbih, gbhh, gruH, gruO, t);
    seq_mlp_kernel<<<BATCH_, 256, 0, stream>>>(gruO, smW1, smb1, smW2, smb2, smW3, smb3, seqlg);

    // ---- graph branch
    const int MB = (N_NODES + 63) / 64;   // 782
    linear_kernel<<<dim3(MB, D_ / 64), 256, 0, stream>>>(x, proj_W, proj_b, h0, h, N_NODES, DIN_, D_);
    for (int l = 0; l < L_LAYERS; l++) {
        // acc = h @ Ws[l].T + bs[l]
        linear_kernel<<<dim3(MB, D_ / 64), 256, 0, stream>>>(h, Ws + (size_t)l * D_ * D_, bs + l * D_,
                                                             accb, nullptr, N_NODES, D_, D_);
        for (int r = 0; r < R_TYPES; r++) {
            int lr = l * R_TYPES + r;
            // tx = h @ Wr[l][r].T
            linear_kernel<<<dim3(MB, D_ / 64), 256, 0, stream>>>(h, Wr + (size_t)lr * D_ * D_, nullptr,
                                                                 txb, nullptr, N_NODES, D_, D_);
            attn_score_kernel<<<E_EDGES / 64, 256, 0, stream>>>(h, bsrc, bdst, boff, r,
                aW1 + (size_t)lr * 128 * 512, ab1 + lr * 128, aW2 + lr * 128, ab2 + lr, em, lr, sbuf);
            bucket_max_kernel<<<256, 256, 0, stream>>>(sbuf, boff, r, &red[lr * 2]);
            bucket_sum_kernel<<<256, 256, 0, stream>>>(sbuf, boff, r, &red[lr * 2], (float*)&red[lr * 2 + 1]);
            message_kernel<<<4096, 256, 0, stream>>>(sbuf, txb, bsrc, bdst, boff, r,
                &red[lr * 2], (const float*)&red[lr * 2 + 1], imp, l, accb);
        }
        finalize_kernel<<<(N_NODES + 3) / 4, 256, 0, stream>>>(accb, h0, ln_g + l * D_, ln_b + l * D_, h, N_NODES);
    }

    // ---- pooling + heads
    pool_kernel<<<N_NODES, 256, 0, stream>>>(h, batch, pooled, cntb, N_NODES);
    final_mlp_kernel<<<BATCH_, 256, 0, stream>>>(pooled, cntb, gmW1, gmb1, gmW2, gmb2, gmW3, gmb3, seqlg, out);
}

// Round 2
// 5865.191 us; speedup vs baseline: 1.6275x; 1.6275x over previous
//
#include <hip/hip_runtime.h>
#include <math.h>

#define N_NODES 50000
#define E_EDGES 320000
#define DIN_    768
#define D_      256
#define R_TYPES 4
#define L_LAYERS 3
#define BATCH_  64
#define T_STEPS 6
#define SD_     128
#define SH_     256
#define NC_     14
#define ALPHA_  0.15f
#define NBLK_B  1250   // bucketing blocks: 1250*256 == E_EDGES exactly

// ---------------- generic fp32 linear: out[m,n] = sum_k A[m,k]*W[n,k] + bias[n]
// 64x64 tile, BK=16, 256 threads, 4x4 per thread. Optionally dual-store (h0 and h).
__global__ __launch_bounds__(256) void linear_kernel(
    const float* __restrict__ A, const float* __restrict__ W,
    const float* __restrict__ bias, float* __restrict__ out,
    float* __restrict__ out2, int M, int K, int N)
{
    __shared__ float As[16][68];
    __shared__ float Bs[16][68];
    const int m0 = blockIdx.x * 64;
    const int n0 = blockIdx.y * 64;
    const int tid = threadIdx.x;
    const int kk = tid & 15;   // k within tile
    const int rr = tid >> 4;   // row group
    const int tx = tid & 15, ty = tid >> 4;
    float acc[4][4] = {};
    for (int k0 = 0; k0 < K; k0 += 16) {
        #pragma unroll
        for (int i = 0; i < 4; i++) {
            int m = m0 + rr + 16 * i;
            As[kk][rr + 16 * i] = (m < M) ? A[(size_t)m * K + k0 + kk] : 0.0f;
            int n = n0 + rr + 16 * i;
            Bs[kk][rr + 16 * i] = W[(size_t)n * K + k0 + kk];
        }
        __syncthreads();
        #pragma unroll
        for (int k = 0; k < 16; k++) {
            float4 a4 = *(const float4*)&As[k][ty * 4];
            float4 b4 = *(const float4*)&Bs[k][tx * 4];
            float av[4] = {a4.x, a4.y, a4.z, a4.w};
            float bv[4] = {b4.x, b4.y, b4.z, b4.w};
            #pragma unroll
            for (int i = 0; i < 4; i++)
                #pragma unroll
                for (int j = 0; j < 4; j++)
                    acc[i][j] += av[i] * bv[j];
        }
        __syncthreads();
    }
    #pragma unroll
    for (int i = 0; i < 4; i++) {
        int m = m0 + ty * 4 + i;
        if (m >= M) continue;
        #pragma unroll
        for (int j = 0; j < 4; j++) {
            int n = n0 + tx * 4 + j;
            float v = acc[i][j] + (bias ? bias[n] : 0.0f);
            out[(size_t)m * N + n] = v;
            if (out2) out2[(size_t)m * N + n] = v;
        }
    }
}

// ---------------- edge bucketing by type: deterministic 3-phase, zero global atomics
__global__ __launch_bounds__(256) void bucket_count2(const int* __restrict__ et,
                                                     int* __restrict__ blockCnt)
{
    int b = blockIdx.x, tid = threadIdx.x;
    int r = et[b * 256 + tid];
    int lane = tid & 63, wv = tid >> 6;
    __shared__ int wcnt[4][4];   // [wave][type]
    #pragma unroll
    for (int t = 0; t < 4; t++) {
        unsigned long long m = __ballot(r == t);
        if (lane == 0) wcnt[wv][t] = __popcll(m);
    }
    __syncthreads();
    if (tid < 4)
        blockCnt[b * 4 + tid] = wcnt[0][tid] + wcnt[1][tid] + wcnt[2][tid] + wcnt[3][tid];
}

__global__ void bucket_scan(const int* __restrict__ blockCnt, int* __restrict__ boff,
                            int* __restrict__ basePerBlock)
{
    __shared__ int tot[4];
    int t = threadIdx.x;
    if (t < 4) {
        int s = 0;
        for (int b = 0; b < NBLK_B; b++) s += blockCnt[b * 4 + t];
        tot[t] = s;
    }
    __syncthreads();
    if (t == 0) {
        int o = 0;
        for (int r = 0; r < 4; r++) { boff[r] = o; o += tot[r]; }
        boff[4] = o;
    }
    __syncthreads();
    if (t < 4) {
        int run = boff[t];
        for (int b = 0; b < NBLK_B; b++) { basePerBlock[b * 4 + t] = run; run += blockCnt[b * 4 + t]; }
    }
}

__global__ __launch_bounds__(256) void bucket_scatter2(
    const int* __restrict__ ei, const int* __restrict__ et,
    const int* __restrict__ basePerBlock, int* __restrict__ bsrc, int* __restrict__ bdst)
{
    int b = blockIdx.x, tid = threadIdx.x;
    int e = b * 256 + tid;
    int r = et[e];
    int lane = tid & 63, wv = tid >> 6;
    __shared__ int wcnt[4][4];
    int myrank = 0;
    unsigned long long ltmask = (1ull << lane) - 1ull;
    #pragma unroll
    for (int t = 0; t < 4; t++) {
        unsigned long long m = __ballot(r == t);
        if (r == t) myrank = __popcll(m & ltmask);
        if (lane == 0) wcnt[wv][t] = __popcll(m);
    }
    __syncthreads();
    int wbase = 0;
    for (int w = 0; w < wv; w++) wbase += wcnt[w][r];
    int pos = basePerBlock[b * 4 + r] + wbase + myrank;
    bsrc[pos] = ei[e];             // src = edge_index[0]
    bdst[pos] = ei[E_EDGES + e];   // dst = edge_index[1]
}

__global__ void embmean_kernel(const float* __restrict__ emb, float* __restrict__ em)
{
    int lr = threadIdx.x;
    if (lr < L_LAYERS * R_TYPES) {
        float s = 0.0f;
        for (int k = 0; k < 64; k++) s += emb[lr * 64 + k];
        em[lr] = s / 64.0f;
    }
}

// ---------------- fused attention score: s[p] = lrelu(relu(cat@W1.T + b1)@W2 + b2) + embmean
// cat[e] = [h[dst], h[src]] (512). tile: 64 edges x 128 hidden, BK=16.
__global__ __launch_bounds__(256) void attn_score_kernel(
    const float* __restrict__ h, const int* __restrict__ bsrc, const int* __restrict__ bdst,
    const int* __restrict__ boff, int r,
    const float* __restrict__ W1, const float* __restrict__ b1,
    const float* __restrict__ W2, const float* __restrict__ b2s,
    const float* __restrict__ em, int lr, float* __restrict__ sbuf)
{
    const int off = boff[r];
    const int n_r = boff[r + 1] - off;
    const int p0 = blockIdx.x * 64;
    if (p0 >= n_r) return;
    __shared__ int nd_d[64], nd_s[64];
    __shared__ float Cs[16][68];
    __shared__ float W1s[16][132];
    __shared__ float red[64][17];
    const int tid = threadIdx.x;
    if (tid < 64) nd_d[tid] = (p0 + tid < n_r) ? bdst[off + p0 + tid] : 0;
    else if (tid < 128) { int t = tid - 64; nd_s[t] = (p0 + t < n_r) ? bsrc[off + p0 + t] : 0; }
    __syncthreads();
    const int kk = tid & 15, rr = tid >> 4;
    const int tx = tid & 15, ty = tid >> 4;
    float acc[4][8] = {};
    for (int k0 = 0; k0 < 512; k0 += 16) {
        const bool useDst = (k0 < 256);
        const int koff = useDst ? k0 : (k0 - 256);
        #pragma unroll
        for (int i = 0; i < 4; i++) {
            int le = rr + 16 * i;
            int node = useDst ? nd_d[le] : nd_s[le];
            Cs[kk][le] = h[(size_t)node * D_ + koff + kk];
        }
        #pragma unroll
        for (int i = 0; i < 8; i++) {
            int n = rr + 16 * i;
            W1s[kk][n] = W1[(size_t)n * 512 + k0 + kk];
        }
        __syncthreads();
        #pragma unroll
        for (int k = 0; k < 16; k++) {
            float4 c4 = *(const float4*)&Cs[k][ty * 4];
            float4 wa = *(const float4*)&W1s[k][tx * 8];
            float4 wb = *(const float4*)&W1s[k][tx * 8 + 4];
            float cv[4] = {c4.x, c4.y, c4.z, c4.w};
            float wv[8] = {wa.x, wa.y, wa.z, wa.w, wb.x, wb.y, wb.z, wb.w};
            #pragma unroll
            for (int i = 0; i < 4; i++)
                #pragma unroll
                for (int j = 0; j < 8; j++)
                    acc[i][j] += cv[i] * wv[j];
        }
        __syncthreads();
    }
    float part[4] = {0, 0, 0, 0};
    #pragma unroll
    for (int j = 0; j < 8; j++) {
        int n = tx * 8 + j;
        float b1v = b1[n], w2v = W2[n];
        #pragma unroll
        for (int i = 0; i < 4; i++) {
            float v = acc[i][j] + b1v;
            v = v > 0.0f ? v : 0.0f;
            part[i] += v * w2v;
        }
    }
    #pragma unroll
    for (int i = 0; i < 4; i++) red[ty * 4 + i][tx] = part[i];
    __syncthreads();
    if (tid < 64) {
        float s = 0.0f;
        #pragma unroll
        for (int x = 0; x < 16; x++) s += red[tid][x];
        int p = p0 + tid;
        if (p < n_r) {
            float sv = s + b2s[0];
            sv = sv > 0.0f ? sv : 0.2f * sv;   // leaky_relu(0.2)
            sv += em[lr];
            sbuf[p] = sv;
        }
    }
}

// ---------------- masked-softmax helpers (monotonic uint key for float atomicMax)
__device__ __forceinline__ unsigned fkey(float f) {
    unsigned u = __float_as_uint(f);
    return (u & 0x80000000u) ? ~u : (u | 0x80000000u);
}
__device__ __forceinline__ float fkey_inv(unsigned k) {
    unsigned u = (k & 0x80000000u) ? (k ^ 0x80000000u) : ~k;
    return __uint_as_float(u);
}

__global__ void bucket_max_kernel(const float* __restrict__ sbuf, const int* __restrict__ boff,
                                  int r, unsigned* __restrict__ mx)
{
    int n_r = boff[r + 1] - boff[r];
    float m = -1e30f;
    for (int i = blockIdx.x * blockDim.x + threadIdx.x; i < n_r; i += gridDim.x * blockDim.x)
        m = fmaxf(m, sbuf[i]);
    for (int o = 32; o; o >>= 1) m = fmaxf(m, __shfl_down(m, o));
    __shared__ float wm[4];
    int lane = threadIdx.x & 63, wv = threadIdx.x >> 6;
    if (lane == 0) wm[wv] = m;
    __syncthreads();
    if (threadIdx.x == 0) {
        float b = fmaxf(fmaxf(wm[0], wm[1]), fmaxf(wm[2], wm[3]));
        atomicMax(mx, fkey(b));
    }
}

__global__ void bucket_sum_kernel(const float* __restrict__ sbuf, const int* __restrict__ boff,
                                  int r, const unsigned* __restrict__ mx, float* __restrict__ sum)
{
    int n_r = boff[r + 1] - boff[r];
    float mxf = fkey_inv(*mx);
    float s = 0.0f;
    for (int i = blockIdx.x * blockDim.x + threadIdx.x; i < n_r; i += gridDim.x * blockDim.x)
        s += expf(sbuf[i] - mxf);
    for (int o = 32; o; o >>= 1) s += __shfl_down(s, o);
    __shared__ float wm[4];
    int lane = threadIdx.x & 63, wv = threadIdx.x >> 6;
    if (lane == 0) wm[wv] = s;
    __syncthreads();
    if (threadIdx.x == 0) atomicAdd(sum, wm[0] + wm[1] + wm[2] + wm[3]);
}

// ---------------- message passing: acc[dst] += (1-a)*ew[r] * softmax(s) * tx[src]
__global__ void message_kernel(const float* __restrict__ sbuf, const float* __restrict__ txb,
                               const int* __restrict__ bsrc, const int* __restrict__ bdst,
                               const int* __restrict__ boff, int r,
                               const unsigned* __restrict__ mx, const float* __restrict__ sumv,
                               const float* __restrict__ imp, int l, float* __restrict__ acc)
{
    const int off = boff[r];
    const int n_r = boff[r + 1] - off;
    const float mxf = fkey_inv(*mx);
    const float inv = 1.0f / sumv[0];
    float e0 = expf(imp[l * 4 + 0]), e1 = expf(imp[l * 4 + 1]);
    float e2 = expf(imp[l * 4 + 2]), e3 = expf(imp[l * 4 + 3]);
    float ew = ((r == 0) ? e0 : (r == 1) ? e1 : (r == 2) ? e2 : e3) / (e0 + e1 + e2 + e3);
    const float coef = (1.0f - ALPHA_) * ew;
    const int lane = threadIdx.x & 63;
    const int eslot = threadIdx.x >> 6;
    for (int base = blockIdx.x * 4; base < n_r; base += gridDim.x * 4) {
        int p = base + eslot;
        if (p >= n_r) continue;
        float a = expf(sbuf[p] - mxf) * inv * coef;
        int s = bsrc[off + p], d = bdst[off + p];
        const float* txp = txb + (size_t)s * D_;
        float* ap = acc + (size_t)d * D_;
        #pragma unroll
        for (int j = 0; j < 4; j++) {
            int c = lane + 64 * j;
            atomicAdd(&ap[c], a * txp[c]);
        }
    }
}

// ---------------- out = LN(acc + alpha*h0) -> exact GELU ; one wave per node
__global__ __launch_bounds__(256) void finalize_kernel(
    const float* __restrict__ acc, const float* __restrict__ h0,
    const float* __restrict__ g, const float* __restrict__ b,
    float* __restrict__ h, int Nn)
{
    int node = blockIdx.x * 4 + (threadIdx.x >> 6);
    if (node >= Nn) return;
    int lane = threadIdx.x & 63;
    float v[4];
    float sum = 0.0f;
    #pragma unroll
    for (int j = 0; j < 4; j++) {
        int c = lane + 64 * j;
        v[j] = acc[(size_t)node * D_ + c] + ALPHA_ * h0[(size_t)node * D_ + c];
        sum += v[j];
    }
    #pragma unroll
    for (int o = 32; o; o >>= 1) sum += __shfl_down(sum, o);
    sum = __shfl(sum, 0);
    float mean = sum * (1.0f / 256.0f);
    float sq = 0.0f;
    #pragma unroll
    for (int j = 0; j < 4; j++) { float d = v[j] - mean; sq += d * d; }
    #pragma unroll
    for (int o = 32; o; o >>= 1) sq += __shfl_down(sq, o);
    sq = __shfl(sq, 0);
    float rstd = rsqrtf(sq * (1.0f / 256.0f) + 1e-5f);
    #pragma unroll
    for (int j = 0; j < 4; j++) {
        int c = lane + 64 * j;
        float x = (v[j] - mean) * rstd * g[c] + b[c];
        float ge = 0.5f * x * (1.0f + erff(x * 0.7071067811865475f));
        h[(size_t)node * D_ + c] = ge;
    }
}

// ---------------- graph mean-pool (atomic) + count
__global__ void pool_kernel(const float* __restrict__ h, const int* __restrict__ batch,
                            float* __restrict__ pooled, float* __restrict__ cntb, int Nn)
{
    int node = blockIdx.x;
    if (node >= Nn) return;
    int b = batch[node];
    int c = threadIdx.x;
    atomicAdd(&pooled[b * D_ + c], h[(size_t)node * D_ + c]);
    if (c == 0) atomicAdd(&cntb[b], 1.0f);
}

// ---------------- graph MLP head (+ add seq logits) -> d_out
__global__ __launch_bounds__(256) void final_mlp_kernel(
    const float* __restrict__ pooled, const float* __restrict__ cntb,
    const float* __restrict__ W1, const float* __restrict__ b1,
    const float* __restrict__ W2, const float* __restrict__ b2,
    const float* __restrict__ W3, const float* __restrict__ b3,
    const float* __restrict__ seqlg, float* __restrict__ out)
{
    int b = blockIdx.x;
    int t = threadIdx.x;
    __shared__ float p[256];
    __shared__ float z1[128];
    __shared__ float z2[64];
    float c = cntb[b]; c = c < 1.0f ? 1.0f : c;
    p[t] = pooled[b * 256 + t] / c;
    __syncthreads();
    if (t < 128) {
        float s = b1[t];
        for (int k = 0; k < 256; k++) s += p[k] * W1[t * 256 + k];
        z1[t] = s > 0.0f ? s : 0.0f;
    }
    __syncthreads();
    if (t < 64) {
        float s = b2[t];
        for (int k = 0; k < 128; k++) s += z1[k] * W2[t * 128 + k];
        z2[t] = s > 0.0f ? s : 0.0f;
    }
    __syncthreads();
    if (t < NC_) {
        float s = b3[t];
        for (int k = 0; k < 64; k++) s += z2[k] * W3[t * 64 + k];
        out[b * NC_ + t] = s + seqlg[b * NC_ + t];
    }
}

// ---------------- GRU: one step for both directions; block = (b, dir)
__global__ __launch_bounds__(256) void gru_step_kernel(
    const float* __restrict__ seq, const float* __restrict__ Wih, const float* __restrict__ Whh,
    const float* __restrict__ bih, const float* __restrict__ bhh,
    float* __restrict__ hstate, float* __restrict__ outs, int t)
{
    int blk = blockIdx.x;      // 0..127
    int dir = blk >> 6;
    int b = blk & 63;
    int tin = dir ? (T_STEPS - 1 - t) : t;   // bwd consumes reversed input; output also lands at tin
    const float* Wih_d = Wih + (size_t)dir * (3 * SH_) * SD_;
    const float* Whh_d = Whh + (size_t)dir * (3 * SH_) * SH_;
    const float* bih_d = bih + dir * (3 * SH_);
    const float* bhh_d = bhh + dir * (3 * SH_);
    __shared__ float xt[SD_];
    __shared__ float hs[SH_];
    int j = threadIdx.x;
    if (j < SD_) xt[j] = seq[((size_t)b * T_STEPS + tin) * SD_ + j];
    hs[j] = hstate[((size_t)dir * 64 + b) * SH_ + j];
    __syncthreads();
    float gi[3], gh[3];
    #pragma unroll
    for (int g = 0; g < 3; g++) {
        const float* wrow = Wih_d + (size_t)(g * SH_ + j) * SD_;
        float s = bih_d[g * SH_ + j];
        for (int k = 0; k < SD_; k++) s += xt[k] * wrow[k];
        gi[g] = s;
        const float* hrow = Whh_d + (size_t)(g * SH_ + j) * SH_;
        float s2 = bhh_d[g * SH_ + j];
        for (int k = 0; k < SH_; k++) s2 += hs[k] * hrow[k];
        gh[g] = s2;
    }
    float r = 1.0f / (1.0f + expf(-(gi[0] + gh[0])));
    float z = 1.0f / (1.0f + expf(-(gi[1] + gh[1])));
    float n = tanhf(gi[2] + r * gh[2]);
    float hn = (1.0f - z) * n + z * hs[j];
    hstate[((size_t)dir * 64 + b) * SH_ + j] = hn;
    outs[(((size_t)dir * 64 + b) * T_STEPS + tin) * SH_ + j] = hn;
}

// ---------------- seq branch: mean+max pool over T, 3-layer MLP -> seq logits
__global__ __launch_bounds__(256) void seq_mlp_kernel(
    const float* __restrict__ outs, const float* __restrict__ W1, const float* __restrict__ b1,
    const float* __restrict__ W2, const float* __restrict__ b2,
    const float* __restrict__ W3, const float* __restrict__ b3,
    float* __restrict__ seqlg)
{
    int b = blockIdx.x;
    int t = threadIdx.x;
    __shared__ float z[512];
    __shared__ float z1[256];
    __shared__ float z2[128];
    for (int c = t; c < 512; c += 256) {
        int dir = c >> 8, cc = c & 255;
        float mean = 0.0f, mx = -1e30f;
        for (int tt = 0; tt < T_STEPS; tt++) {
            float v = outs[(((size_t)dir * 64 + b) * T_STEPS + tt) * SH_ + cc];
            mean += v; mx = fmaxf(mx, v);
        }
        z[c] = mean * (1.0f / T_STEPS) + mx;
    }
    __syncthreads();
    {
        float s = b1[t];
        for (int k = 0; k < 512; k++) s += z[k] * W1[t * 512 + k];
        z1[t] = s > 0.0f ? s : 0.0f;
    }
    __syncthreads();
    if (t < 128) {
        float s = b2[t];
        for (int k = 0; k < 256; k++) s += z1[k] * W2[t * 256 + k];
        z2[t] = s > 0.0f ? s : 0.0f;
    }
    __syncthreads();
    if (t < NC_) {
        float s = b3[t];
        for (int k = 0; k < 128; k++) s += z2[k] * W3[t * 128 + k];
        seqlg[b * NC_ + t] = s;
    }
}

extern "C" void kernel_launch(void* const* d_in, const int* in_sizes, int n_in,
                              void* d_out, int out_size, void* d_ws, size_t ws_size,
                              hipStream_t stream)
{
    const float* x      = (const float*)d_in[0];
    const int*   ei     = (const int*)d_in[1];
    const int*   et     = (const int*)d_in[2];
    const int*   batch  = (const int*)d_in[3];
    const float* seq    = (const float*)d_in[4];
    const float* proj_W = (const float*)d_in[5];
    const float* proj_b = (const float*)d_in[6];
    const float* Wr     = (const float*)d_in[7];
    const float* Ws     = (const float*)d_in[8];
    const float* bs     = (const float*)d_in[9];
    const float* aW1    = (const float*)d_in[10];
    const float* ab1    = (const float*)d_in[11];
    const float* aW2    = (const float*)d_in[12];
    const float* ab2    = (const float*)d_in[13];
    const float* emb    = (const float*)d_in[14];
    const float* imp    = (const float*)d_in[15];
    const float* ln_g   = (const float*)d_in[16];
    const float* ln_b   = (const float*)d_in[17];
    const float* gmW1   = (const float*)d_in[18];
    const float* gmb1   = (const float*)d_in[19];
    const float* gmW2   = (const float*)d_in[20];
    const float* gmb2   = (const float*)d_in[21];
    const float* gmW3   = (const float*)d_in[22];
    const float* gmb3   = (const float*)d_in[23];
    const float* gWih   = (const float*)d_in[24];
    const float* gWhh   = (const float*)d_in[25];
    const float* gbih   = (const float*)d_in[26];
    const float* gbhh   = (const float*)d_in[27];
    const float* smW1   = (const float*)d_in[28];
    const float* smb1   = (const float*)d_in[29];
    const float* smW2   = (const float*)d_in[30];
    const float* smb2   = (const float*)d_in[31];
    const float* smW3   = (const float*)d_in[32];
    const float* smb3   = (const float*)d_in[33];
    float* out = (float*)d_out;

    // ---- workspace layout (~211 MB)
    char* ws = (char*)d_ws;
    size_t o = 0;
    auto alloc = [&](size_t bytes) -> void* {
        void* p = ws + o;
        o += (bytes + 1023) & ~(size_t)1023;
        return p;
    };
    float* h0     = (float*)alloc(sizeof(float) * (size_t)N_NODES * D_);
    float* h      = (float*)alloc(sizeof(float) * (size_t)N_NODES * D_);
    float* accb   = (float*)alloc(sizeof(float) * (size_t)N_NODES * D_);
    float* txb    = (float*)alloc(sizeof(float) * (size_t)N_NODES * D_);
    float* sbuf   = (float*)alloc(sizeof(float) * E_EDGES);
    int*   bsrc   = (int*)alloc(sizeof(int) * E_EDGES);
    int*   bdst   = (int*)alloc(sizeof(int) * E_EDGES);
    int*   boff   = (int*)alloc(sizeof(int) * 8);
    int*   blockCnt = (int*)alloc(sizeof(int) * NBLK_B * 4);
    int*   basePerBlock = (int*)alloc(sizeof(int) * NBLK_B * 4);
    unsigned* red = (unsigned*)alloc(sizeof(unsigned) * 32); // per (l,r): [2*lr]=max key, [2*lr+1]=sum(float)
    float* em     = (float*)alloc(sizeof(float) * 16);
    float* seqlg  = (float*)alloc(sizeof(float) * BATCH_ * NC_);
    float* gruH   = (float*)alloc(sizeof(float) * 2 * BATCH_ * SH_);
    float* gruO   = (float*)alloc(sizeof(float) * 2 * BATCH_ * T_STEPS * SH_);
    float* pooled = (float*)alloc(sizeof(float) * BATCH_ * D_);
    float* cntb   = (float*)alloc(sizeof(float) * BATCH_);
    (void)ws_size; (void)in_sizes; (void)n_in; (void)out_size;

    // ---- zero-init (ws is poisoned 0xAA before every timed launch)
    hipMemsetAsync(red, 0, 32 * sizeof(unsigned), stream);          // key 0 < any real fkey; sum = 0.0f
    hipMemsetAsync(gruH, 0, 2 * BATCH_ * SH_ * sizeof(float), stream);
    hipMemsetAsync(pooled, 0, BATCH_ * D_ * sizeof(float), stream);
    hipMemsetAsync(cntb, 0, BATCH_ * sizeof(float), stream);

    // ---- edge bucketing by type (deterministic, no global atomics)
    bucket_count2<<<NBLK_B, 256, 0, stream>>>(et, blockCnt);
    bucket_scan<<<1, 64, 0, stream>>>(blockCnt, boff, basePerBlock);
    bucket_scatter2<<<NBLK_B, 256, 0, stream>>>(ei, et, basePerBlock, bsrc, bdst);
    embmean_kernel<<<1, 64, 0, stream>>>(emb, em);

    // ---- sequence branch
    for (int t = 0; t < T_STEPS; t++)
        gru_step_kernel<<<128, 256, 0, stream>>>(seq, gWih, gWhh, gbih, gbhh, gruH, gruO, t);
    seq_mlp_kernel<<<BATCH_, 256, 0, stream>>>(gruO, smW1, smb1, smW2, smb2, smW3, smb3, seqlg);

    // ---- graph branch
    const int MB = (N_NODES + 63) / 64;   // 782
    linear_kernel<<<dim3(MB, D_ / 64), 256, 0, stream>>>(x, proj_W, proj_b, h0, h, N_NODES, DIN_, D_);
    for (int l = 0; l < L_LAYERS; l++) {
        // acc = h @ Ws[l].T + bs[l]
        linear_kernel<<<dim3(MB, D_ / 64), 256, 0, stream>>>(h, Ws + (size_t)l * D_ * D_, bs + l * D_,
                                                             accb, nullptr, N_NODES, D_, D_);
        for (int r = 0; r < R_TYPES; r++) {
            int lr = l * R_TYPES + r;
            // tx = h @ Wr[l][r].T
            linear_kernel<<<dim3(MB, D_ / 64), 256, 0, stream>>>(h, Wr + (size_t)lr * D_ * D_, nullptr,
                                                                 txb, nullptr, N_NODES, D_, D_);
            attn_score_kernel<<<E_EDGES / 64, 256, 0, stream>>>(h, bsrc, bdst, boff, r,
                aW1 + (size_t)lr * 128 * 512, ab1 + lr * 128, aW2 + lr * 128, ab2 + lr, em, lr, sbuf);
            bucket_max_kernel<<<256, 256, 0, stream>>>(sbuf, boff, r, &red[lr * 2]);
            bucket_sum_kernel<<<256, 256, 0, stream>>>(sbuf, boff, r, &red[lr * 2], (float*)&red[lr * 2 + 1]);
            message_kernel<<<4096, 256, 0, stream>>>(sbuf, txb, bsrc, bdst, boff, r,
                &red[lr * 2], (const float*)&red[lr * 2 + 1], imp, l, accb);
        }
        finalize_kernel<<<(N_NODES + 3) / 4, 256, 0, stream>>>(accb, h0, ln_g + l * D_, ln_b + l * D_, h, N_NODES);
    }

    // ---- pooling + heads
    pool_kernel<<<N_NODES, 256, 0, stream>>>(h, batch, pooled, cntb, N_NODES);
    final_mlp_kernel<<<BATCH_, 256, 0, stream>>>(pooled, cntb, gmW1, gmb1, gmW2, gmb2, gmW3, gmb3, seqlg, out);
}

// Round 3
// 5491.019 us; speedup vs baseline: 1.7384x; 1.0681x over previous
//
#include <hip/hip_runtime.h>
#include <math.h>

#define N_NODES 50000
#define E_EDGES 320000
#define DIN_    768
#define D_      256
#define R_TYPES 4
#define L_LAYERS 3
#define BATCH_  64
#define T_STEPS 6
#define SD_     128
#define SH_     256
#define NC_     14
#define ALPHA_  0.15f
#define NBLK_B  1250   // bucketing blocks: 1250*256 == E_EDGES exactly
#define POOL_CHUNK 256

// ---------------- generic fp32 linear: out[m,n] = sum_k A[m,k]*W[n,k] + bias[n]
// 64x64 tile, BK=16, 256 threads, 4x4 per thread. Optionally dual-store (h0 and h).
__global__ __launch_bounds__(256) void linear_kernel(
    const float* __restrict__ A, const float* __restrict__ W,
    const float* __restrict__ bias, float* __restrict__ out,
    float* __restrict__ out2, int M, int K, int N)
{
    __shared__ float As[16][68];
    __shared__ float Bs[16][68];
    const int m0 = blockIdx.x * 64;
    const int n0 = blockIdx.y * 64;
    const int tid = threadIdx.x;
    const int kk = tid & 15;   // k within tile
    const int rr = tid >> 4;   // row group
    const int tx = tid & 15, ty = tid >> 4;
    float acc[4][4] = {};
    for (int k0 = 0; k0 < K; k0 += 16) {
        #pragma unroll
        for (int i = 0; i < 4; i++) {
            int m = m0 + rr + 16 * i;
            As[kk][rr + 16 * i] = (m < M) ? A[(size_t)m * K + k0 + kk] : 0.0f;
            int n = n0 + rr + 16 * i;
            Bs[kk][rr + 16 * i] = W[(size_t)n * K + k0 + kk];
        }
        __syncthreads();
        #pragma unroll
        for (int k = 0; k < 16; k++) {
            float4 a4 = *(const float4*)&As[k][ty * 4];
            float4 b4 = *(const float4*)&Bs[k][tx * 4];
            float av[4] = {a4.x, a4.y, a4.z, a4.w};
            float bv[4] = {b4.x, b4.y, b4.z, b4.w};
            #pragma unroll
            for (int i = 0; i < 4; i++)
                #pragma unroll
                for (int j = 0; j < 4; j++)
                    acc[i][j] += av[i] * bv[j];
        }
        __syncthreads();
    }
    #pragma unroll
    for (int i = 0; i < 4; i++) {
        int m = m0 + ty * 4 + i;
        if (m >= M) continue;
        #pragma unroll
        for (int j = 0; j < 4; j++) {
            int n = n0 + tx * 4 + j;
            float v = acc[i][j] + (bias ? bias[n] : 0.0f);
            out[(size_t)m * N + n] = v;
            if (out2) out2[(size_t)m * N + n] = v;
        }
    }
}

// ---------------- edge bucketing by type: deterministic 3-phase, zero global atomics
__global__ __launch_bounds__(256) void bucket_count2(const int* __restrict__ et,
                                                     int* __restrict__ blockCnt)
{
    int b = blockIdx.x, tid = threadIdx.x;
    int r = et[b * 256 + tid];
    int lane = tid & 63, wv = tid >> 6;
    __shared__ int wcnt[4][4];   // [wave][type]
    #pragma unroll
    for (int t = 0; t < 4; t++) {
        unsigned long long m = __ballot(r == t);
        if (lane == 0) wcnt[wv][t] = __popcll(m);
    }
    __syncthreads();
    if (tid < 4)
        blockCnt[b * 4 + tid] = wcnt[0][tid] + wcnt[1][tid] + wcnt[2][tid] + wcnt[3][tid];
}

__global__ void bucket_scan(const int* __restrict__ blockCnt, int* __restrict__ boff,
                            int* __restrict__ basePerBlock)
{
    __shared__ int tot[4];
    int t = threadIdx.x;
    if (t < 4) {
        int s = 0;
        for (int b = 0; b < NBLK_B; b++) s += blockCnt[b * 4 + t];
        tot[t] = s;
    }
    __syncthreads();
    if (t == 0) {
        int o = 0;
        for (int r = 0; r < 4; r++) { boff[r] = o; o += tot[r]; }
        boff[4] = o;
    }
    __syncthreads();
    if (t < 4) {
        int run = boff[t];
        for (int b = 0; b < NBLK_B; b++) { basePerBlock[b * 4 + t] = run; run += blockCnt[b * 4 + t]; }
    }
}

__global__ __launch_bounds__(256) void bucket_scatter2(
    const int* __restrict__ ei, const int* __restrict__ et,
    const int* __restrict__ basePerBlock, int* __restrict__ bsrc, int* __restrict__ bdst)
{
    int b = blockIdx.x, tid = threadIdx.x;
    int e = b * 256 + tid;
    int r = et[e];
    int lane = tid & 63, wv = tid >> 6;
    __shared__ int wcnt[4][4];
    int myrank = 0;
    unsigned long long ltmask = (1ull << lane) - 1ull;
    #pragma unroll
    for (int t = 0; t < 4; t++) {
        unsigned long long m = __ballot(r == t);
        if (r == t) myrank = __popcll(m & ltmask);
        if (lane == 0) wcnt[wv][t] = __popcll(m);
    }
    __syncthreads();
    int wbase = 0;
    for (int w = 0; w < wv; w++) wbase += wcnt[w][r];
    int pos = basePerBlock[b * 4 + r] + wbase + myrank;
    bsrc[pos] = ei[e];             // src = edge_index[0]
    bdst[pos] = ei[E_EDGES + e];   // dst = edge_index[1]
}

__global__ void embmean_kernel(const float* __restrict__ emb, float* __restrict__ em)
{
    int lr = threadIdx.x;
    if (lr < L_LAYERS * R_TYPES) {
        float s = 0.0f;
        for (int k = 0; k < 64; k++) s += emb[lr * 64 + k];
        em[lr] = s / 64.0f;
    }
}

// ---------------- fused attention score: s[p] = lrelu(relu(cat@W1.T + b1)@W2 + b2) + embmean
// cat[e] = [h[dst], h[src]] (512). tile: 64 edges x 128 hidden, BK=16.
__global__ __launch_bounds__(256) void attn_score_kernel(
    const float* __restrict__ h, const int* __restrict__ bsrc, const int* __restrict__ bdst,
    const int* __restrict__ boff, int r,
    const float* __restrict__ W1, const float* __restrict__ b1,
    const float* __restrict__ W2, const float* __restrict__ b2s,
    const float* __restrict__ em, int lr, float* __restrict__ sbuf)
{
    const int off = boff[r];
    const int n_r = boff[r + 1] - off;
    const int p0 = blockIdx.x * 64;
    if (p0 >= n_r) return;
    __shared__ int nd_d[64], nd_s[64];
    __shared__ float Cs[16][68];
    __shared__ float W1s[16][132];
    __shared__ float red[64][17];
    const int tid = threadIdx.x;
    if (tid < 64) nd_d[tid] = (p0 + tid < n_r) ? bdst[off + p0 + tid] : 0;
    else if (tid < 128) { int t = tid - 64; nd_s[t] = (p0 + t < n_r) ? bsrc[off + p0 + t] : 0; }
    __syncthreads();
    const int kk = tid & 15, rr = tid >> 4;
    const int tx = tid & 15, ty = tid >> 4;
    float acc[4][8] = {};
    for (int k0 = 0; k0 < 512; k0 += 16) {
        const bool useDst = (k0 < 256);
        const int koff = useDst ? k0 : (k0 - 256);
        #pragma unroll
        for (int i = 0; i < 4; i++) {
            int le = rr + 16 * i;
            int node = useDst ? nd_d[le] : nd_s[le];
            Cs[kk][le] = h[(size_t)node * D_ + koff + kk];
        }
        #pragma unroll
        for (int i = 0; i < 8; i++) {
            int n = rr + 16 * i;
            W1s[kk][n] = W1[(size_t)n * 512 + k0 + kk];
        }
        __syncthreads();
        #pragma unroll
        for (int k = 0; k < 16; k++) {
            float4 c4 = *(const float4*)&Cs[k][ty * 4];
            float4 wa = *(const float4*)&W1s[k][tx * 8];
            float4 wb = *(const float4*)&W1s[k][tx * 8 + 4];
            float cv[4] = {c4.x, c4.y, c4.z, c4.w};
            float wv[8] = {wa.x, wa.y, wa.z, wa.w, wb.x, wb.y, wb.z, wb.w};
            #pragma unroll
            for (int i = 0; i < 4; i++)
                #pragma unroll
                for (int j = 0; j < 8; j++)
                    acc[i][j] += cv[i] * wv[j];
        }
        __syncthreads();
    }
    float part[4] = {0, 0, 0, 0};
    #pragma unroll
    for (int j = 0; j < 8; j++) {
        int n = tx * 8 + j;
        float b1v = b1[n], w2v = W2[n];
        #pragma unroll
        for (int i = 0; i < 4; i++) {
            float v = acc[i][j] + b1v;
            v = v > 0.0f ? v : 0.0f;
            part[i] += v * w2v;
        }
    }
    #pragma unroll
    for (int i = 0; i < 4; i++) red[ty * 4 + i][tx] = part[i];
    __syncthreads();
    if (tid < 64) {
        float s = 0.0f;
        #pragma unroll
        for (int x = 0; x < 16; x++) s += red[tid][x];
        int p = p0 + tid;
        if (p < n_r) {
            float sv = s + b2s[0];
            sv = sv > 0.0f ? sv : 0.2f * sv;   // leaky_relu(0.2)
            sv += em[lr];
            sbuf[p] = sv;
        }
    }
}

// ---------------- masked-softmax helpers (monotonic uint key for float atomicMax)
__device__ __forceinline__ unsigned fkey(float f) {
    unsigned u = __float_as_uint(f);
    return (u & 0x80000000u) ? ~u : (u | 0x80000000u);
}
__device__ __forceinline__ float fkey_inv(unsigned k) {
    unsigned u = (k & 0x80000000u) ? (k ^ 0x80000000u) : ~k;
    return __uint_as_float(u);
}

__global__ void bucket_max_kernel(const float* __restrict__ sbuf, const int* __restrict__ boff,
                                  int r, unsigned* __restrict__ mx)
{
    int n_r = boff[r + 1] - boff[r];
    float m = -1e30f;
    for (int i = blockIdx.x * blockDim.x + threadIdx.x; i < n_r; i += gridDim.x * blockDim.x)
        m = fmaxf(m, sbuf[i]);
    for (int o = 32; o; o >>= 1) m = fmaxf(m, __shfl_down(m, o));
    __shared__ float wm[4];
    int lane = threadIdx.x & 63, wv = threadIdx.x >> 6;
    if (lane == 0) wm[wv] = m;
    __syncthreads();
    if (threadIdx.x == 0) {
        float b = fmaxf(fmaxf(wm[0], wm[1]), fmaxf(wm[2], wm[3]));
        atomicMax(mx, fkey(b));
    }
}

__global__ void bucket_sum_kernel(const float* __restrict__ sbuf, const int* __restrict__ boff,
                                  int r, const unsigned* __restrict__ mx, float* __restrict__ sum)
{
    int n_r = boff[r + 1] - boff[r];
    float mxf = fkey_inv(*mx);
    float s = 0.0f;
    for (int i = blockIdx.x * blockDim.x + threadIdx.x; i < n_r; i += gridDim.x * blockDim.x)
        s += expf(sbuf[i] - mxf);
    for (int o = 32; o; o >>= 1) s += __shfl_down(s, o);
    __shared__ float wm[4];
    int lane = threadIdx.x & 63, wv = threadIdx.x >> 6;
    if (lane == 0) wm[wv] = s;
    __syncthreads();
    if (threadIdx.x == 0) atomicAdd(sum, wm[0] + wm[1] + wm[2] + wm[3]);
}

// ---------------- message passing: acc[dst] += (1-a)*ew[r] * softmax(s) * tx[src]
__global__ void message_kernel(const float* __restrict__ sbuf, const float* __restrict__ txb,
                               const int* __restrict__ bsrc, const int* __restrict__ bdst,
                               const int* __restrict__ boff, int r,
                               const unsigned* __restrict__ mx, const float* __restrict__ sumv,
                               const float* __restrict__ imp, int l, float* __restrict__ acc)
{
    const int off = boff[r];
    const int n_r = boff[r + 1] - off;
    const float mxf = fkey_inv(*mx);
    const float inv = 1.0f / sumv[0];
    float e0 = expf(imp[l * 4 + 0]), e1 = expf(imp[l * 4 + 1]);
    float e2 = expf(imp[l * 4 + 2]), e3 = expf(imp[l * 4 + 3]);
    float ew = ((r == 0) ? e0 : (r == 1) ? e1 : (r == 2) ? e2 : e3) / (e0 + e1 + e2 + e3);
    const float coef = (1.0f - ALPHA_) * ew;
    const int lane = threadIdx.x & 63;
    const int eslot = threadIdx.x >> 6;
    for (int base = blockIdx.x * 4; base < n_r; base += gridDim.x * 4) {
        int p = base + eslot;
        if (p >= n_r) continue;
        float a = expf(sbuf[p] - mxf) * inv * coef;
        int s = bsrc[off + p], d = bdst[off + p];
        const float* txp = txb + (size_t)s * D_;
        float* ap = acc + (size_t)d * D_;
        #pragma unroll
        for (int j = 0; j < 4; j++) {
            int c = lane + 64 * j;
            atomicAdd(&ap[c], a * txp[c]);
        }
    }
}

// ---------------- out = LN(acc + alpha*h0) -> exact GELU ; one wave per node
__global__ __launch_bounds__(256) void finalize_kernel(
    const float* __restrict__ acc, const float* __restrict__ h0,
    const float* __restrict__ g, const float* __restrict__ b,
    float* __restrict__ h, int Nn)
{
    int node = blockIdx.x * 4 + (threadIdx.x >> 6);
    if (node >= Nn) return;
    int lane = threadIdx.x & 63;
    float v[4];
    float sum = 0.0f;
    #pragma unroll
    for (int j = 0; j < 4; j++) {
        int c = lane + 64 * j;
        v[j] = acc[(size_t)node * D_ + c] + ALPHA_ * h0[(size_t)node * D_ + c];
        sum += v[j];
    }
    #pragma unroll
    for (int o = 32; o; o >>= 1) sum += __shfl_down(sum, o);
    sum = __shfl(sum, 0);
    float mean = sum * (1.0f / 256.0f);
    float sq = 0.0f;
    #pragma unroll
    for (int j = 0; j < 4; j++) { float d = v[j] - mean; sq += d * d; }
    #pragma unroll
    for (int o = 32; o; o >>= 1) sq += __shfl_down(sq, o);
    sq = __shfl(sq, 0);
    float rstd = rsqrtf(sq * (1.0f / 256.0f) + 1e-5f);
    #pragma unroll
    for (int j = 0; j < 4; j++) {
        int c = lane + 64 * j;
        float x = (v[j] - mean) * rstd * g[c] + b[c];
        float ge = 0.5f * x * (1.0f + erff(x * 0.7071067811865475f));
        h[(size_t)node * D_ + c] = ge;
    }
}

// ---------------- graph mean-pool: segmented register reduction (batch is sorted)
// block = 256-node chunk; thread c owns channel c; flush one atomic per segment boundary.
__global__ __launch_bounds__(256) void pool_seg_kernel(
    const float* __restrict__ h, const int* __restrict__ batch,
    float* __restrict__ pooled, float* __restrict__ cntb, int Nn)
{
    int start = blockIdx.x * POOL_CHUNK;
    if (start >= Nn) return;
    int end = start + POOL_CHUNK; if (end > Nn) end = Nn;
    int c = threadIdx.x;
    __shared__ int bseg[POOL_CHUNK];
    if (start + c < Nn) bseg[c] = batch[start + c];
    __syncthreads();
    float acc = 0.0f;
    int cur = bseg[0];
    int segcnt = 0;
    for (int node = start; node < end; node++) {
        int b = bseg[node - start];
        if (b != cur) {
            atomicAdd(&pooled[cur * D_ + c], acc);
            if (c == 0) atomicAdd(&cntb[cur], (float)segcnt);
            acc = 0.0f; segcnt = 0; cur = b;
        }
        acc += h[(size_t)node * D_ + c];
        segcnt++;
    }
    atomicAdd(&pooled[cur * D_ + c], acc);
    if (c == 0) atomicAdd(&cntb[cur], (float)segcnt);
}

// ---------------- graph MLP head (+ add seq logits) -> d_out
__global__ __launch_bounds__(256) void final_mlp_kernel(
    const float* __restrict__ pooled, const float* __restrict__ cntb,
    const float* __restrict__ W1, const float* __restrict__ b1,
    const float* __restrict__ W2, const float* __restrict__ b2,
    const float* __restrict__ W3, const float* __restrict__ b3,
    const float* __restrict__ seqlg, float* __restrict__ out)
{
    int b = blockIdx.x;
    int t = threadIdx.x;
    __shared__ float p[256];
    __shared__ float z1[128];
    __shared__ float z2[64];
    float c = cntb[b]; c = c < 1.0f ? 1.0f : c;
    p[t] = pooled[b * 256 + t] / c;
    __syncthreads();
    if (t < 128) {
        float s = b1[t];
        for (int k = 0; k < 256; k++) s += p[k] * W1[t * 256 + k];
        z1[t] = s > 0.0f ? s : 0.0f;
    }
    __syncthreads();
    if (t < 64) {
        float s = b2[t];
        for (int k = 0; k < 128; k++) s += z1[k] * W2[t * 128 + k];
        z2[t] = s > 0.0f ? s : 0.0f;
    }
    __syncthreads();
    if (t < NC_) {
        float s = b3[t];
        for (int k = 0; k < 64; k++) s += z2[k] * W3[t * 64 + k];
        out[b * NC_ + t] = s + seqlg[b * NC_ + t];
    }
}

// ---------------- GRU: one step for both directions; block = (b, dir)
__global__ __launch_bounds__(256) void gru_step_kernel(
    const float* __restrict__ seq, const float* __restrict__ Wih, const float* __restrict__ Whh,
    const float* __restrict__ bih, const float* __restrict__ bhh,
    float* __restrict__ hstate, float* __restrict__ outs, int t)
{
    int blk = blockIdx.x;      // 0..127
    int dir = blk >> 6;
    int b = blk & 63;
    int tin = dir ? (T_STEPS - 1 - t) : t;   // bwd consumes reversed input; output also lands at tin
    const float* Wih_d = Wih + (size_t)dir * (3 * SH_) * SD_;
    const float* Whh_d = Whh + (size_t)dir * (3 * SH_) * SH_;
    const float* bih_d = bih + dir * (3 * SH_);
    const float* bhh_d = bhh + dir * (3 * SH_);
    __shared__ float xt[SD_];
    __shared__ float hs[SH_];
    int j = threadIdx.x;
    if (j < SD_) xt[j] = seq[((size_t)b * T_STEPS + tin) * SD_ + j];
    hs[j] = hstate[((size_t)dir * 64 + b) * SH_ + j];
    __syncthreads();
    float gi[3], gh[3];
    #pragma unroll
    for (int g = 0; g < 3; g++) {
        const float* wrow = Wih_d + (size_t)(g * SH_ + j) * SD_;
        float s = bih_d[g * SH_ + j];
        for (int k = 0; k < SD_; k++) s += xt[k] * wrow[k];
        gi[g] = s;
        const float* hrow = Whh_d + (size_t)(g * SH_ + j) * SH_;
        float s2 = bhh_d[g * SH_ + j];
        for (int k = 0; k < SH_; k++) s2 += hs[k] * hrow[k];
        gh[g] = s2;
    }
    float r = 1.0f / (1.0f + expf(-(gi[0] + gh[0])));
    float z = 1.0f / (1.0f + expf(-(gi[1] + gh[1])));
    float n = tanhf(gi[2] + r * gh[2]);
    float hn = (1.0f - z) * n + z * hs[j];
    hstate[((size_t)dir * 64 + b) * SH_ + j] = hn;
    outs[(((size_t)dir * 64 + b) * T_STEPS + tin) * SH_ + j] = hn;
}

// ---------------- seq branch: mean+max pool over T, 3-layer MLP -> seq logits
__global__ __launch_bounds__(256) void seq_mlp_kernel(
    const float* __restrict__ outs, const float* __restrict__ W1, const float* __restrict__ b1,
    const float* __restrict__ W2, const float* __restrict__ b2,
    const float* __restrict__ W3, const float* __restrict__ b3,
    float* __restrict__ seqlg)
{
    int b = blockIdx.x;
    int t = threadIdx.x;
    __shared__ float z[512];
    __shared__ float z1[256];
    __shared__ float z2[128];
    for (int c = t; c < 512; c += 256) {
        int dir = c >> 8, cc = c & 255;
        float mean = 0.0f, mx = -1e30f;
        for (int tt = 0; tt < T_STEPS; tt++) {
            float v = outs[(((size_t)dir * 64 + b) * T_STEPS + tt) * SH_ + cc];
            mean += v; mx = fmaxf(mx, v);
        }
        z[c] = mean * (1.0f / T_STEPS) + mx;
    }
    __syncthreads();
    {
        float s = b1[t];
        for (int k = 0; k < 512; k++) s += z[k] * W1[t * 512 + k];
        z1[t] = s > 0.0f ? s : 0.0f;
    }
    __syncthreads();
    if (t < 128) {
        float s = b2[t];
        for (int k = 0; k < 256; k++) s += z1[k] * W2[t * 256 + k];
        z2[t] = s > 0.0f ? s : 0.0f;
    }
    __syncthreads();
    if (t < NC_) {
        float s = b3[t];
        for (int k = 0; k < 128; k++) s += z2[k] * W3[t * 128 + k];
        seqlg[b * NC_ + t] = s;
    }
}

extern "C" void kernel_launch(void* const* d_in, const int* in_sizes, int n_in,
                              void* d_out, int out_size, void* d_ws, size_t ws_size,
                              hipStream_t stream)
{
    const float* x      = (const float*)d_in[0];
    const int*   ei     = (const int*)d_in[1];
    const int*   et     = (const int*)d_in[2];
    const int*   batch  = (const int*)d_in[3];
    const float* seq    = (const float*)d_in[4];
    const float* proj_W = (const float*)d_in[5];
    const float* proj_b = (const float*)d_in[6];
    const float* Wr     = (const float*)d_in[7];
    const float* Ws     = (const float*)d_in[8];
    const float* bs     = (const float*)d_in[9];
    const float* aW1    = (const float*)d_in[10];
    const float* ab1    = (const float*)d_in[11];
    const float* aW2    = (const float*)d_in[12];
    const float* ab2    = (const float*)d_in[13];
    const float* emb    = (const float*)d_in[14];
    const float* imp    = (const float*)d_in[15];
    const float* ln_g   = (const float*)d_in[16];
    const float* ln_b   = (const float*)d_in[17];
    const float* gmW1   = (const float*)d_in[18];
    const float* gmb1   = (const float*)d_in[19];
    const float* gmW2   = (const float*)d_in[20];
    const float* gmb2   = (const float*)d_in[21];
    const float* gmW3   = (const float*)d_in[22];
    const float* gmb3   = (const float*)d_in[23];
    const float* gWih   = (const float*)d_in[24];
    const float* gWhh   = (const float*)d_in[25];
    const float* gbih   = (const float*)d_in[26];
    const float* gbhh   = (const float*)d_in[27];
    const float* smW1   = (const float*)d_in[28];
    const float* smb1   = (const float*)d_in[29];
    const float* smW2   = (const float*)d_in[30];
    const float* smb2   = (const float*)d_in[31];
    const float* smW3   = (const float*)d_in[32];
    const float* smb3   = (const float*)d_in[33];
    float* out = (float*)d_out;

    // ---- workspace layout (~211 MB)
    char* ws = (char*)d_ws;
    size_t o = 0;
    auto alloc = [&](size_t bytes) -> void* {
        void* p = ws + o;
        o += (bytes + 1023) & ~(size_t)1023;
        return p;
    };
    float* h0     = (float*)alloc(sizeof(float) * (size_t)N_NODES * D_);
    float* h      = (float*)alloc(sizeof(float) * (size_t)N_NODES * D_);
    float* accb   = (float*)alloc(sizeof(float) * (size_t)N_NODES * D_);
    float* txb    = (float*)alloc(sizeof(float) * (size_t)N_NODES * D_);
    float* sbuf   = (float*)alloc(sizeof(float) * E_EDGES);
    int*   bsrc   = (int*)alloc(sizeof(int) * E_EDGES);
    int*   bdst   = (int*)alloc(sizeof(int) * E_EDGES);
    int*   boff   = (int*)alloc(sizeof(int) * 8);
    int*   blockCnt = (int*)alloc(sizeof(int) * NBLK_B * 4);
    int*   basePerBlock = (int*)alloc(sizeof(int) * NBLK_B * 4);
    unsigned* red = (unsigned*)alloc(sizeof(unsigned) * 32); // per (l,r): [2*lr]=max key, [2*lr+1]=sum(float)
    float* em     = (float*)alloc(sizeof(float) * 16);
    float* seqlg  = (float*)alloc(sizeof(float) * BATCH_ * NC_);
    float* gruH   = (float*)alloc(sizeof(float) * 2 * BATCH_ * SH_);
    float* gruO   = (float*)alloc(sizeof(float) * 2 * BATCH_ * T_STEPS * SH_);
    float* pooled = (float*)alloc(sizeof(float) * BATCH_ * D_);
    float* cntb   = (float*)alloc(sizeof(float) * BATCH_);
    (void)ws_size; (void)in_sizes; (void)n_in; (void)out_size;

    // ---- zero-init (ws is poisoned 0xAA before every timed launch)
    hipMemsetAsync(red, 0, 32 * sizeof(unsigned), stream);          // key 0 < any real fkey; sum = 0.0f
    hipMemsetAsync(gruH, 0, 2 * BATCH_ * SH_ * sizeof(float), stream);
    hipMemsetAsync(pooled, 0, BATCH_ * D_ * sizeof(float), stream);
    hipMemsetAsync(cntb, 0, BATCH_ * sizeof(float), stream);

    // ---- edge bucketing by type (deterministic, no global atomics)
    bucket_count2<<<NBLK_B, 256, 0, stream>>>(et, blockCnt);
    bucket_scan<<<1, 64, 0, stream>>>(blockCnt, boff, basePerBlock);
    bucket_scatter2<<<NBLK_B, 256, 0, stream>>>(ei, et, basePerBlock, bsrc, bdst);
    embmean_kernel<<<1, 64, 0, stream>>>(emb, em);

    // ---- sequence branch
    for (int t = 0; t < T_STEPS; t++)
        gru_step_kernel<<<128, 256, 0, stream>>>(seq, gWih, gWhh, gbih, gbhh, gruH, gruO, t);
    seq_mlp_kernel<<<BATCH_, 256, 0, stream>>>(gruO, smW1, smb1, smW2, smb2, smW3, smb3, seqlg);

    // ---- graph branch
    const int MB = (N_NODES + 63) / 64;   // 782
    linear_kernel<<<dim3(MB, D_ / 64), 256, 0, stream>>>(x, proj_W, proj_b, h0, h, N_NODES, DIN_, D_);
    for (int l = 0; l < L_LAYERS; l++) {
        // acc = h @ Ws[l].T + bs[l]
        linear_kernel<<<dim3(MB, D_ / 64), 256, 0, stream>>>(h, Ws + (size_t)l * D_ * D_, bs + l * D_,
                                                             accb, nullptr, N_NODES, D_, D_);
        for (int r = 0; r < R_TYPES; r++) {
            int lr = l * R_TYPES + r;
            // tx = h @ Wr[l][r].T
            linear_kernel<<<dim3(MB, D_ / 64), 256, 0, stream>>>(h, Wr + (size_t)lr * D_ * D_, nullptr,
                                                                 txb, nullptr, N_NODES, D_, D_);
            attn_score_kernel<<<E_EDGES / 64, 256, 0, stream>>>(h, bsrc, bdst, boff, r,
                aW1 + (size_t)lr * 128 * 512, ab1 + lr * 128, aW2 + lr * 128, ab2 + lr, em, lr, sbuf);
            bucket_max_kernel<<<256, 256, 0, stream>>>(sbuf, boff, r, &red[lr * 2]);
            bucket_sum_kernel<<<256, 256, 0, stream>>>(sbuf, boff, r, &red[lr * 2], (float*)&red[lr * 2 + 1]);
            message_kernel<<<4096, 256, 0, stream>>>(sbuf, txb, bsrc, bdst, boff, r,
                &red[lr * 2], (const float*)&red[lr * 2 + 1], imp, l, accb);
        }
        finalize_kernel<<<(N_NODES + 3) / 4, 256, 0, stream>>>(accb, h0, ln_g + l * D_, ln_b + l * D_, h, N_NODES);
    }

    // ---- pooling + heads
    pool_seg_kernel<<<(N_NODES + POOL_CHUNK - 1) / POOL_CHUNK, 256, 0, stream>>>(h, batch, pooled, cntb, N_NODES);
    final_mlp_kernel<<<BATCH_, 256, 0, stream>>>(pooled, cntb, gmW1, gmb1, gmW2, gmb2, gmW3, gmb3, seqlg, out);
}

// Round 4
// 2783.627 us; speedup vs baseline: 3.4291x; 1.9726x over previous
//
#include <hip/hip_runtime.h>
#include <math.h>

#define N_NODES 50000
#define E_EDGES 320000
#define DIN_    768
#define D_      256
#define R_TYPES 4
#define L_LAYERS 3
#define BATCH_  64
#define T_STEPS 6
#define SD_     128
#define SH_     256
#define NC_     14
#define ALPHA_  0.15f
#define NBLK_B  1250   // bucketing blocks: 1250*256 == E_EDGES exactly
#define POOL_CHUNK 256

typedef __bf16 bf16_t;
typedef bf16_t bf16x8_t __attribute__((ext_vector_type(8)));
typedef float  f32x4_t  __attribute__((ext_vector_type(4)));

__device__ __forceinline__ f32x4_t mfma16(bf16x8_t a, bf16x8_t b, f32x4_t c) {
    return __builtin_amdgcn_mfma_f32_16x16x32_bf16(a, b, c, 0, 0, 0);
}

// ---------------- fp32 -> bf16 conversion (vector4, n % 4 == 0)
__global__ void f2b_kernel(const float* __restrict__ src, bf16_t* __restrict__ dst, int n4)
{
    for (int i = blockIdx.x * blockDim.x + threadIdx.x; i < n4; i += gridDim.x * blockDim.x) {
        float4 v = ((const float4*)src)[i];
        bf16_t o[4] = {(bf16_t)v.x, (bf16_t)v.y, (bf16_t)v.z, (bf16_t)v.w};
        *(ulong1*)&dst[i * 4] = *(ulong1*)o;
    }
}

// ---------------- bf16 MFMA linear: out[m,n] = sum_k A[m,k]*W[n,k] + bias
// 64x64 tile, 4 waves (2x2), each wave 32x32 via 4 mfma accs. K multiple of 32.
__global__ __launch_bounds__(256) void linear_mfma(
    const bf16_t* __restrict__ A, const bf16_t* __restrict__ W,
    const float* __restrict__ bias, float* __restrict__ outf,
    bf16_t* __restrict__ outb, int M, int K, int N)
{
    __shared__ bf16_t As[64][40];
    __shared__ bf16_t Bs[64][40];
    const int m0 = blockIdx.x * 64;
    const int n0 = blockIdx.y * 64;
    const int tid = threadIdx.x;
    const int wave = tid >> 6, lane = tid & 63;
    const int wy = wave >> 1, wx = wave & 1;           // wave tile: (wy*32, wx*32)
    const int q = lane >> 4, c = lane & 15;            // mfma frag coords
    const int srow = tid >> 2, skq = tid & 3;          // staging: row 0..63, 8-elem chunk 0..3

    f32x4_t acc[2][2] = {};
    for (int k0 = 0; k0 < K; k0 += 32) {
        // stage A tile (guarded) and B tile
        {
            int m = m0 + srow;
            bf16x8_t av = {};
            if (m < M) av = *(const bf16x8_t*)&A[(size_t)m * K + k0 + skq * 8];
            *(bf16x8_t*)&As[srow][skq * 8] = av;
            *(bf16x8_t*)&Bs[srow][skq * 8] = *(const bf16x8_t*)&W[(size_t)(n0 + srow) * K + k0 + skq * 8];
        }
        __syncthreads();
        bf16x8_t af[2], bf[2];
        #pragma unroll
        for (int mt = 0; mt < 2; mt++) af[mt] = *(const bf16x8_t*)&As[wy * 32 + mt * 16 + c][q * 8];
        #pragma unroll
        for (int nt = 0; nt < 2; nt++) bf[nt] = *(const bf16x8_t*)&Bs[wx * 32 + nt * 16 + c][q * 8];
        #pragma unroll
        for (int mt = 0; mt < 2; mt++)
            #pragma unroll
            for (int nt = 0; nt < 2; nt++)
                acc[mt][nt] = mfma16(af[mt], bf[nt], acc[mt][nt]);
        __syncthreads();
    }
    // epilogue: C/D layout col=lane&15, row=(lane>>4)*4+reg
    #pragma unroll
    for (int mt = 0; mt < 2; mt++) {
        #pragma unroll
        for (int nt = 0; nt < 2; nt++) {
            int n = n0 + wx * 32 + nt * 16 + c;
            float bv = bias ? bias[n] : 0.0f;
            #pragma unroll
            for (int j = 0; j < 4; j++) {
                int m = m0 + wy * 32 + mt * 16 + q * 4 + j;
                if (m < M) {
                    float v = acc[mt][nt][j] + bv;
                    outf[(size_t)m * N + n] = v;
                    if (outb) outb[(size_t)m * N + n] = (bf16_t)v;
                }
            }
        }
    }
}

// ---------------- edge bucketing by type: deterministic 3-phase, zero global atomics
__global__ __launch_bounds__(256) void bucket_count2(const int* __restrict__ et,
                                                     int* __restrict__ blockCnt)
{
    int b = blockIdx.x, tid = threadIdx.x;
    int r = et[b * 256 + tid];
    int lane = tid & 63, wv = tid >> 6;
    __shared__ int wcnt[4][4];   // [wave][type]
    #pragma unroll
    for (int t = 0; t < 4; t++) {
        unsigned long long m = __ballot(r == t);
        if (lane == 0) wcnt[wv][t] = __popcll(m);
    }
    __syncthreads();
    if (tid < 4)
        blockCnt[b * 4 + tid] = wcnt[0][tid] + wcnt[1][tid] + wcnt[2][tid] + wcnt[3][tid];
}

__global__ void bucket_scan(const int* __restrict__ blockCnt, int* __restrict__ boff,
                            int* __restrict__ basePerBlock)
{
    __shared__ int tot[4];
    int t = threadIdx.x;
    if (t < 4) {
        int s = 0;
        for (int b = 0; b < NBLK_B; b++) s += blockCnt[b * 4 + t];
        tot[t] = s;
    }
    __syncthreads();
    if (t == 0) {
        int o = 0;
        for (int r = 0; r < 4; r++) { boff[r] = o; o += tot[r]; }
        boff[4] = o;
    }
    __syncthreads();
    if (t < 4) {
        int run = boff[t];
        for (int b = 0; b < NBLK_B; b++) { basePerBlock[b * 4 + t] = run; run += blockCnt[b * 4 + t]; }
    }
}

__global__ __launch_bounds__(256) void bucket_scatter2(
    const int* __restrict__ ei, const int* __restrict__ et,
    const int* __restrict__ basePerBlock, int* __restrict__ bsrc, int* __restrict__ bdst)
{
    int b = blockIdx.x, tid = threadIdx.x;
    int e = b * 256 + tid;
    int r = et[e];
    int lane = tid & 63, wv = tid >> 6;
    __shared__ int wcnt[4][4];
    int myrank = 0;
    unsigned long long ltmask = (1ull << lane) - 1ull;
    #pragma unroll
    for (int t = 0; t < 4; t++) {
        unsigned long long m = __ballot(r == t);
        if (r == t) myrank = __popcll(m & ltmask);
        if (lane == 0) wcnt[wv][t] = __popcll(m);
    }
    __syncthreads();
    int wbase = 0;
    for (int w = 0; w < wv; w++) wbase += wcnt[w][r];
    int pos = basePerBlock[b * 4 + r] + wbase + myrank;
    bsrc[pos] = ei[e];             // src = edge_index[0]
    bdst[pos] = ei[E_EDGES + e];   // dst = edge_index[1]
}

__global__ void embmean_kernel(const float* __restrict__ emb, float* __restrict__ em)
{
    int lr = threadIdx.x;
    if (lr < L_LAYERS * R_TYPES) {
        float s = 0.0f;
        for (int k = 0; k < 64; k++) s += emb[lr * 64 + k];
        em[lr] = s / 64.0f;
    }
}

// ---------------- MFMA attention score: s = lrelu(relu(cat@W1.T + b1)@W2 + b2) + embmean
// 64 edges x 128 hidden per block; cat[e] = [hb[dst] | hb[src]] (K=512).
// Wave w owns 16 edges; 8 n-tiles of 16. Epilogue reduces over hidden via shfl_xor.
__global__ __launch_bounds__(256) void attn_mfma(
    const bf16_t* __restrict__ hb, const int* __restrict__ bsrc, const int* __restrict__ bdst,
    const int* __restrict__ boff, int r,
    const bf16_t* __restrict__ W1, const float* __restrict__ b1,
    const float* __restrict__ W2, const float* __restrict__ b2s,
    const float* __restrict__ em, int lr, float* __restrict__ sbuf)
{
    const int off = boff[r];
    const int n_r = boff[r + 1] - off;
    const int p0 = blockIdx.x * 64;
    if (p0 >= n_r) return;
    __shared__ int nd_d[64], nd_s[64];
    __shared__ bf16_t Acat[64][40];
    __shared__ bf16_t Bs[128][40];
    const int tid = threadIdx.x;
    if (tid < 64) nd_d[tid] = (p0 + tid < n_r) ? bdst[off + p0 + tid] : 0;
    else if (tid < 128) { int t = tid - 64; nd_s[t] = (p0 + t < n_r) ? bsrc[off + p0 + t] : 0; }
    __syncthreads();
    const int wave = tid >> 6, lane = tid & 63;
    const int q = lane >> 4, c = lane & 15;
    const int srow = tid >> 2, skq = tid & 3;   // A staging: edge 0..63, chunk 0..3

    f32x4_t acc[8] = {};
    for (int ks = 0; ks < 16; ks++) {
        // gather cat tile: k = ks*32 .. +32 ; dst half for ks<8, src half for ks>=8
        {
            int node = (ks < 8) ? nd_d[srow] : nd_s[srow];
            int koffm = (ks & 7) * 32 + skq * 8;
            *(bf16x8_t*)&Acat[srow][skq * 8] = *(const bf16x8_t*)&hb[(size_t)node * D_ + koffm];
            // W1 tile: 128 rows x 32 k ; 512 chunks, 2 per thread
            #pragma unroll
            for (int s = 0; s < 2; s++) {
                int slot = tid + s * 256;
                int nrow = slot >> 2, nkq = slot & 3;
                *(bf16x8_t*)&Bs[nrow][nkq * 8] = *(const bf16x8_t*)&W1[(size_t)nrow * 512 + ks * 32 + nkq * 8];
            }
        }
        __syncthreads();
        bf16x8_t af = *(const bf16x8_t*)&Acat[wave * 16 + c][q * 8];
        #pragma unroll
        for (int nt = 0; nt < 8; nt++) {
            bf16x8_t bfv = *(const bf16x8_t*)&Bs[nt * 16 + c][q * 8];
            acc[nt] = mfma16(af, bfv, acc[nt]);
        }
        __syncthreads();
    }
    // epilogue: z[row][n] = acc + b1[n]; relu; * W2[n]; sum over n (128)
    float part[4] = {0, 0, 0, 0};
    #pragma unroll
    for (int nt = 0; nt < 8; nt++) {
        int n = nt * 16 + c;
        float b1v = b1[n], w2v = W2[n];
        #pragma unroll
        for (int j = 0; j < 4; j++) {
            float v = acc[nt][j] + b1v;
            v = v > 0.0f ? v : 0.0f;
            part[j] += v * w2v;
        }
    }
    #pragma unroll
    for (int j = 0; j < 4; j++) {
        #pragma unroll
        for (int mask = 1; mask <= 8; mask <<= 1)
            part[j] += __shfl_xor(part[j], mask);
    }
    if (c == 0) {
        float b2v = b2s[0], emv = em[lr];
        #pragma unroll
        for (int j = 0; j < 4; j++) {
            int p = p0 + wave * 16 + q * 4 + j;
            if (p < n_r) {
                float sv = part[j] + b2v;
                sv = sv > 0.0f ? sv : 0.2f * sv;   // leaky_relu(0.2)
                sbuf[p] = sv + emv;
            }
        }
    }
}

// ---------------- masked-softmax helpers (monotonic uint key for float atomicMax)
__device__ __forceinline__ unsigned fkey(float f) {
    unsigned u = __float_as_uint(f);
    return (u & 0x80000000u) ? ~u : (u | 0x80000000u);
}
__device__ __forceinline__ float fkey_inv(unsigned k) {
    unsigned u = (k & 0x80000000u) ? (k ^ 0x80000000u) : ~k;
    return __uint_as_float(u);
}

__global__ void bucket_max_kernel(const float* __restrict__ sbuf, const int* __restrict__ boff,
                                  int r, unsigned* __restrict__ mx)
{
    int n_r = boff[r + 1] - boff[r];
    float m = -1e30f;
    for (int i = blockIdx.x * blockDim.x + threadIdx.x; i < n_r; i += gridDim.x * blockDim.x)
        m = fmaxf(m, sbuf[i]);
    for (int o = 32; o; o >>= 1) m = fmaxf(m, __shfl_down(m, o));
    __shared__ float wm[4];
    int lane = threadIdx.x & 63, wv = threadIdx.x >> 6;
    if (lane == 0) wm[wv] = m;
    __syncthreads();
    if (threadIdx.x == 0) {
        float b = fmaxf(fmaxf(wm[0], wm[1]), fmaxf(wm[2], wm[3]));
        atomicMax(mx, fkey(b));
    }
}

__global__ void bucket_sum_kernel(const float* __restrict__ sbuf, const int* __restrict__ boff,
                                  int r, const unsigned* __restrict__ mx, float* __restrict__ sum)
{
    int n_r = boff[r + 1] - boff[r];
    float mxf = fkey_inv(*mx);
    float s = 0.0f;
    for (int i = blockIdx.x * blockDim.x + threadIdx.x; i < n_r; i += gridDim.x * blockDim.x)
        s += expf(sbuf[i] - mxf);
    for (int o = 32; o; o >>= 1) s += __shfl_down(s, o);
    __shared__ float wm[4];
    int lane = threadIdx.x & 63, wv = threadIdx.x >> 6;
    if (lane == 0) wm[wv] = s;
    __syncthreads();
    if (threadIdx.x == 0) atomicAdd(sum, wm[0] + wm[1] + wm[2] + wm[3]);
}

// ---------------- message passing: acc[dst] += (1-a)*ew[r] * softmax(s) * tx[src]
__global__ void message_kernel(const float* __restrict__ sbuf, const float* __restrict__ txb,
                               const int* __restrict__ bsrc, const int* __restrict__ bdst,
                               const int* __restrict__ boff, int r,
                               const unsigned* __restrict__ mx, const float* __restrict__ sumv,
                               const float* __restrict__ imp, int l, float* __restrict__ acc)
{
    const int off = boff[r];
    const int n_r = boff[r + 1] - off;
    const float mxf = fkey_inv(*mx);
    const float inv = 1.0f / sumv[0];
    float e0 = expf(imp[l * 4 + 0]), e1 = expf(imp[l * 4 + 1]);
    float e2 = expf(imp[l * 4 + 2]), e3 = expf(imp[l * 4 + 3]);
    float ew = ((r == 0) ? e0 : (r == 1) ? e1 : (r == 2) ? e2 : e3) / (e0 + e1 + e2 + e3);
    const float coef = (1.0f - ALPHA_) * ew;
    const int lane = threadIdx.x & 63;
    const int eslot = threadIdx.x >> 6;
    for (int base = blockIdx.x * 4; base < n_r; base += gridDim.x * 4) {
        int p = base + eslot;
        if (p >= n_r) continue;
        float a = expf(sbuf[p] - mxf) * inv * coef;
        int s = bsrc[off + p], d = bdst[off + p];
        const float* txp = txb + (size_t)s * D_;
        float* ap = acc + (size_t)d * D_;
        #pragma unroll
        for (int j = 0; j < 4; j++) {
            int c = lane + 64 * j;
            atomicAdd(&ap[c], a * txp[c]);
        }
    }
}

// ---------------- out = LN(acc + alpha*h0) -> exact GELU ; one wave per node
__global__ __launch_bounds__(256) void finalize_kernel(
    const float* __restrict__ acc, const float* __restrict__ h0,
    const float* __restrict__ g, const float* __restrict__ b,
    float* __restrict__ h, bf16_t* __restrict__ hb, int Nn)
{
    int node = blockIdx.x * 4 + (threadIdx.x >> 6);
    if (node >= Nn) return;
    int lane = threadIdx.x & 63;
    float v[4];
    float sum = 0.0f;
    #pragma unroll
    for (int j = 0; j < 4; j++) {
        int c = lane + 64 * j;
        v[j] = acc[(size_t)node * D_ + c] + ALPHA_ * h0[(size_t)node * D_ + c];
        sum += v[j];
    }
    #pragma unroll
    for (int o = 32; o; o >>= 1) sum += __shfl_down(sum, o);
    sum = __shfl(sum, 0);
    float mean = sum * (1.0f / 256.0f);
    float sq = 0.0f;
    #pragma unroll
    for (int j = 0; j < 4; j++) { float d = v[j] - mean; sq += d * d; }
    #pragma unroll
    for (int o = 32; o; o >>= 1) sq += __shfl_down(sq, o);
    sq = __shfl(sq, 0);
    float rstd = rsqrtf(sq * (1.0f / 256.0f) + 1e-5f);
    #pragma unroll
    for (int j = 0; j < 4; j++) {
        int c = lane + 64 * j;
        float x = (v[j] - mean) * rstd * g[c] + b[c];
        float ge = 0.5f * x * (1.0f + erff(x * 0.7071067811865475f));
        h[(size_t)node * D_ + c] = ge;
        hb[(size_t)node * D_ + c] = (bf16_t)ge;
    }
}

// ---------------- graph mean-pool: segmented register reduction (batch is sorted)
__global__ __launch_bounds__(256) void pool_seg_kernel(
    const float* __restrict__ h, const int* __restrict__ batch,
    float* __restrict__ pooled, float* __restrict__ cntb, int Nn)
{
    int start = blockIdx.x * POOL_CHUNK;
    if (start >= Nn) return;
    int end = start + POOL_CHUNK; if (end > Nn) end = Nn;
    int c = threadIdx.x;
    __shared__ int bseg[POOL_CHUNK];
    if (start + c < Nn) bseg[c] = batch[start + c];
    __syncthreads();
    float acc = 0.0f;
    int cur = bseg[0];
    int segcnt = 0;
    for (int node = start; node < end; node++) {
        int b = bseg[node - start];
        if (b != cur) {
            atomicAdd(&pooled[cur * D_ + c], acc);
            if (c == 0) atomicAdd(&cntb[cur], (float)segcnt);
            acc = 0.0f; segcnt = 0; cur = b;
        }
        acc += h[(size_t)node * D_ + c];
        segcnt++;
    }
    atomicAdd(&pooled[cur * D_ + c], acc);
    if (c == 0) atomicAdd(&cntb[cur], (float)segcnt);
}

// ---------------- graph MLP head (+ add seq logits) -> d_out
__global__ __launch_bounds__(256) void final_mlp_kernel(
    const float* __restrict__ pooled, const float* __restrict__ cntb,
    const float* __restrict__ W1, const float* __restrict__ b1,
    const float* __restrict__ W2, const float* __restrict__ b2,
    const float* __restrict__ W3, const float* __restrict__ b3,
    const float* __restrict__ seqlg, float* __restrict__ out)
{
    int b = blockIdx.x;
    int t = threadIdx.x;
    __shared__ float p[256];
    __shared__ float z1[128];
    __shared__ float z2[64];
    float c = cntb[b]; c = c < 1.0f ? 1.0f : c;
    p[t] = pooled[b * 256 + t] / c;
    __syncthreads();
    if (t < 128) {
        float s = b1[t];
        for (int k = 0; k < 256; k++) s += p[k] * W1[t * 256 + k];
        z1[t] = s > 0.0f ? s : 0.0f;
    }
    __syncthreads();
    if (t < 64) {
        float s = b2[t];
        for (int k = 0; k < 128; k++) s += z1[k] * W2[t * 128 + k];
        z2[t] = s > 0.0f ? s : 0.0f;
    }
    __syncthreads();
    if (t < NC_) {
        float s = b3[t];
        for (int k = 0; k < 64; k++) s += z2[k] * W3[t * 64 + k];
        out[b * NC_ + t] = s + seqlg[b * NC_ + t];
    }
}

// ---------------- GRU: one step for both directions; block = (b, dir)
__global__ __launch_bounds__(256) void gru_step_kernel(
    const float* __restrict__ seq, const float* __restrict__ Wih, const float* __restrict__ Whh,
    const float* __restrict__ bih, const float* __restrict__ bhh,
    float* __restrict__ hstate, float* __restrict__ outs, int t)
{
    int blk = blockIdx.x;      // 0..127
    int dir = blk >> 6;
    int b = blk & 63;
    int tin = dir ? (T_STEPS - 1 - t) : t;   // bwd consumes reversed input; output also lands at tin
    const float* Wih_d = Wih + (size_t)dir * (3 * SH_) * SD_;
    const float* Whh_d = Whh + (size_t)dir * (3 * SH_) * SH_;
    const float* bih_d = bih + dir * (3 * SH_);
    const float* bhh_d = bhh + dir * (3 * SH_);
    __shared__ float xt[SD_];
    __shared__ float hs[SH_];
    int j = threadIdx.x;
    if (j < SD_) xt[j] = seq[((size_t)b * T_STEPS + tin) * SD_ + j];
    hs[j] = hstate[((size_t)dir * 64 + b) * SH_ + j];
    __syncthreads();
    float gi[3], gh[3];
    #pragma unroll
    for (int g = 0; g < 3; g++) {
        const float* wrow = Wih_d + (size_t)(g * SH_ + j) * SD_;
        float s = bih_d[g * SH_ + j];
        for (int k = 0; k < SD_; k++) s += xt[k] * wrow[k];
        gi[g] = s;
        const float* hrow = Whh_d + (size_t)(g * SH_ + j) * SH_;
        float s2 = bhh_d[g * SH_ + j];
        for (int k = 0; k < SH_; k++) s2 += hs[k] * hrow[k];
        gh[g] = s2;
    }
    float r = 1.0f / (1.0f + expf(-(gi[0] + gh[0])));
    float z = 1.0f / (1.0f + expf(-(gi[1] + gh[1])));
    float n = tanhf(gi[2] + r * gh[2]);
    float hn = (1.0f - z) * n + z * hs[j];
    hstate[((size_t)dir * 64 + b) * SH_ + j] = hn;
    outs[(((size_t)dir * 64 + b) * T_STEPS + tin) * SH_ + j] = hn;
}

// ---------------- seq branch: mean+max pool over T, 3-layer MLP -> seq logits
__global__ __launch_bounds__(256) void seq_mlp_kernel(
    const float* __restrict__ outs, const float* __restrict__ W1, const float* __restrict__ b1,
    const float* __restrict__ W2, const float* __restrict__ b2,
    const float* __restrict__ W3, const float* __restrict__ b3,
    float* __restrict__ seqlg)
{
    int b = blockIdx.x;
    int t = threadIdx.x;
    __shared__ float z[512];
    __shared__ float z1[256];
    __shared__ float z2[128];
    for (int c = t; c < 512; c += 256) {
        int dir = c >> 8, cc = c & 255;
        float mean = 0.0f, mx = -1e30f;
        for (int tt = 0; tt < T_STEPS; tt++) {
            float v = outs[(((size_t)dir * 64 + b) * T_STEPS + tt) * SH_ + cc];
            mean += v; mx = fmaxf(mx, v);
        }
        z[c] = mean * (1.0f / T_STEPS) + mx;
    }
    __syncthreads();
    {
        float s = b1[t];
        for (int k = 0; k < 512; k++) s += z[k] * W1[t * 512 + k];
        z1[t] = s > 0.0f ? s : 0.0f;
    }
    __syncthreads();
    if (t < 128) {
        float s = b2[t];
        for (int k = 0; k < 256; k++) s += z1[k] * W2[t * 256 + k];
        z2[t] = s > 0.0f ? s : 0.0f;
    }
    __syncthreads();
    if (t < NC_) {
        float s = b3[t];
        for (int k = 0; k < 128; k++) s += z2[k] * W3[t * 128 + k];
        seqlg[b * NC_ + t] = s;
    }
}

extern "C" void kernel_launch(void* const* d_in, const int* in_sizes, int n_in,
                              void* d_out, int out_size, void* d_ws, size_t ws_size,
                              hipStream_t stream)
{
    const float* x      = (const float*)d_in[0];
    const int*   ei     = (const int*)d_in[1];
    const int*   et     = (const int*)d_in[2];
    const int*   batch  = (const int*)d_in[3];
    const float* seq    = (const float*)d_in[4];
    const float* proj_W = (const float*)d_in[5];
    const float* proj_b = (const float*)d_in[6];
    const float* Wr     = (const float*)d_in[7];
    const float* Ws     = (const float*)d_in[8];
    const float* bs     = (const float*)d_in[9];
    const float* aW1    = (const float*)d_in[10];
    const float* ab1    = (const float*)d_in[11];
    const float* aW2    = (const float*)d_in[12];
    const float* ab2    = (const float*)d_in[13];
    const float* emb    = (const float*)d_in[14];
    const float* imp    = (const float*)d_in[15];
    const float* ln_g   = (const float*)d_in[16];
    const float* ln_b   = (const float*)d_in[17];
    const float* gmW1   = (const float*)d_in[18];
    const float* gmb1   = (const float*)d_in[19];
    const float* gmW2   = (const float*)d_in[20];
    const float* gmb2   = (const float*)d_in[21];
    const float* gmW3   = (const float*)d_in[22];
    const float* gmb3   = (const float*)d_in[23];
    const float* gWih   = (const float*)d_in[24];
    const float* gWhh   = (const float*)d_in[25];
    const float* gbih   = (const float*)d_in[26];
    const float* gbhh   = (const float*)d_in[27];
    const float* smW1   = (const float*)d_in[28];
    const float* smb1   = (const float*)d_in[29];
    const float* smW2   = (const float*)d_in[30];
    const float* smb2   = (const float*)d_in[31];
    const float* smW3   = (const float*)d_in[32];
    const float* smb3   = (const float*)d_in[33];
    float* out = (float*)d_out;

    // ---- workspace layout (~320 MB)
    char* ws = (char*)d_ws;
    size_t o = 0;
    auto alloc = [&](size_t bytes) -> void* {
        void* p = ws + o;
        o += (bytes + 1023) & ~(size_t)1023;
        return p;
    };
    float*  h0     = (float*)alloc(sizeof(float) * (size_t)N_NODES * D_);
    float*  h      = (float*)alloc(sizeof(float) * (size_t)N_NODES * D_);
    float*  accb   = (float*)alloc(sizeof(float) * (size_t)N_NODES * D_);
    float*  txb    = (float*)alloc(sizeof(float) * (size_t)N_NODES * D_);
    bf16_t* xb     = (bf16_t*)alloc(sizeof(bf16_t) * (size_t)N_NODES * DIN_);
    bf16_t* hbb    = (bf16_t*)alloc(sizeof(bf16_t) * (size_t)N_NODES * D_);
    bf16_t* projWb = (bf16_t*)alloc(sizeof(bf16_t) * D_ * DIN_);
    bf16_t* Wrb    = (bf16_t*)alloc(sizeof(bf16_t) * L_LAYERS * R_TYPES * D_ * D_);
    bf16_t* Wsb    = (bf16_t*)alloc(sizeof(bf16_t) * L_LAYERS * D_ * D_);
    bf16_t* aW1b   = (bf16_t*)alloc(sizeof(bf16_t) * L_LAYERS * R_TYPES * 128 * 512);
    float*  sbuf   = (float*)alloc(sizeof(float) * E_EDGES);
    int*    bsrc   = (int*)alloc(sizeof(int) * E_EDGES);
    int*    bdst   = (int*)alloc(sizeof(int) * E_EDGES);
    int*    boff   = (int*)alloc(sizeof(int) * 8);
    int*    blockCnt = (int*)alloc(sizeof(int) * NBLK_B * 4);
    int*    basePerBlock = (int*)alloc(sizeof(int) * NBLK_B * 4);
    unsigned* red  = (unsigned*)alloc(sizeof(unsigned) * 32);
    float*  em     = (float*)alloc(sizeof(float) * 16);
    float*  seqlg  = (float*)alloc(sizeof(float) * BATCH_ * NC_);
    float*  gruH   = (float*)alloc(sizeof(float) * 2 * BATCH_ * SH_);
    float*  gruO   = (float*)alloc(sizeof(float) * 2 * BATCH_ * T_STEPS * SH_);
    float*  pooled = (float*)alloc(sizeof(float) * BATCH_ * D_);
    float*  cntb   = (float*)alloc(sizeof(float) * BATCH_);
    (void)ws_size; (void)in_sizes; (void)n_in; (void)out_size;

    // ---- zero-init (ws is poisoned 0xAA before every timed launch)
    hipMemsetAsync(red, 0, 32 * sizeof(unsigned), stream);
    hipMemsetAsync(gruH, 0, 2 * BATCH_ * SH_ * sizeof(float), stream);
    hipMemsetAsync(pooled, 0, BATCH_ * D_ * sizeof(float), stream);
    hipMemsetAsync(cntb, 0, BATCH_ * sizeof(float), stream);

    // ---- bf16 conversions (once per launch)
    f2b_kernel<<<2048, 256, 0, stream>>>(x, xb, N_NODES * DIN_ / 4);
    f2b_kernel<<<64, 256, 0, stream>>>(proj_W, projWb, D_ * DIN_ / 4);
    f2b_kernel<<<256, 256, 0, stream>>>(Wr, Wrb, L_LAYERS * R_TYPES * D_ * D_ / 4);
    f2b_kernel<<<64, 256, 0, stream>>>(Ws, Wsb, L_LAYERS * D_ * D_ / 4);
    f2b_kernel<<<256, 256, 0, stream>>>(aW1, aW1b, L_LAYERS * R_TYPES * 128 * 512 / 4);

    // ---- edge bucketing by type (deterministic, no global atomics)
    bucket_count2<<<NBLK_B, 256, 0, stream>>>(et, blockCnt);
    bucket_scan<<<1, 64, 0, stream>>>(blockCnt, boff, basePerBlock);
    bucket_scatter2<<<NBLK_B, 256, 0, stream>>>(ei, et, basePerBlock, bsrc, bdst);
    embmean_kernel<<<1, 64, 0, stream>>>(emb, em);

    // ---- sequence branch
    for (int t = 0; t < T_STEPS; t++)
        gru_step_kernel<<<128, 256, 0, stream>>>(seq, gWih, gWhh, gbih, gbhh, gruH, gruO, t);
    seq_mlp_kernel<<<BATCH_, 256, 0, stream>>>(gruO, smW1, smb1, smW2, smb2, smW3, smb3, seqlg);

    // ---- graph branch
    const int MB = (N_NODES + 63) / 64;   // 782
    // proj: h0 (fp32) + hb (bf16)
    linear_mfma<<<dim3(MB, D_ / 64), 256, 0, stream>>>(xb, projWb, proj_b, h0, hbb, N_NODES, DIN_, D_);
    for (int l = 0; l < L_LAYERS; l++) {
        // acc = h @ Ws[l].T + bs[l]
        linear_mfma<<<dim3(MB, D_ / 64), 256, 0, stream>>>(hbb, Wsb + (size_t)l * D_ * D_, bs + l * D_,
                                                           accb, nullptr, N_NODES, D_, D_);
        for (int r = 0; r < R_TYPES; r++) {
            int lr = l * R_TYPES + r;
            // tx = h @ Wr[l][r].T
            linear_mfma<<<dim3(MB, D_ / 64), 256, 0, stream>>>(hbb, Wrb + (size_t)lr * D_ * D_, nullptr,
                                                               txb, nullptr, N_NODES, D_, D_);
            attn_mfma<<<E_EDGES / 64, 256, 0, stream>>>(hbb, bsrc, bdst, boff, r,
                aW1b + (size_t)lr * 128 * 512, ab1 + lr * 128, aW2 + lr * 128, ab2 + lr, em, lr, sbuf);
            bucket_max_kernel<<<256, 256, 0, stream>>>(sbuf, boff, r, &red[lr * 2]);
            bucket_sum_kernel<<<256, 256, 0, stream>>>(sbuf, boff, r, &red[lr * 2], (float*)&red[lr * 2 + 1]);
            message_kernel<<<4096, 256, 0, stream>>>(sbuf, txb, bsrc, bdst, boff, r,
                &red[lr * 2], (const float*)&red[lr * 2 + 1], imp, l, accb);
        }
        finalize_kernel<<<(N_NODES + 3) / 4, 256, 0, stream>>>(accb, h0, ln_g + l * D_, ln_b + l * D_, h, hbb, N_NODES);
    }

    // ---- pooling + heads
    pool_seg_kernel<<<(N_NODES + POOL_CHUNK - 1) / POOL_CHUNK, 256, 0, stream>>>(h, batch, pooled, cntb, N_NODES);
    final_mlp_kernel<<<BATCH_, 256, 0, stream>>>(pooled, cntb, gmW1, gmb1, gmW2, gmb2, gmW3, gmb3, seqlg, out);
}